// Round 15
// baseline (7856.508 us; speedup 1.0000x reference)
//
#include <hip/hip_runtime.h>
#include <math.h>

// Persistent cooperative 2-layer LSTM. Round 15: WAVE-AUTONOMOUS engines.
// Each wave computes FULL-K for a 16-batch x (4-col x 4-gate) tile; the 16x16
// D-tile holds all 4 gates of 64 cells (1 cell/lane) after an in-wave 4x4
// shuffle transpose. NO __syncthreads / NO LDS exchange in the main loops.
// Per-WAVE flags: flags[domain][cg*4+wid]; consumers poll mtile-matched lines
// only. x read directly from global (L2-resident) with in-loop cvt (4 chunks).
// Rings fragment-major (R13), plain b128 reads + per-step agent-acquire fence,
// agent write-through stores. Domains/backpressure as R11-14 (depth-4 rings,
// L0 ahead, F1>=t-2 backpressure). Split precision: Whi*hhi+Whi*hlo+Wlo*hhi.
//
// Wave (mtile=wid>>1, ntile=wid&1): batches mtile*16..+16, cols
// colbase+ntile*4..+4 (x4 gates). W LDS ntile-major: c=((nt*NC+ch)*4+ks)*16+n.
//
// ws layout (bytes): flags 4 domains x 256 lines x 64B @0 (64KB);
// uints @16384*4=65536: r0h[4][2][8192], r0l, r1h, r1l (256KB/plane, 1MB).

#define TT 512
#define NWG 256

typedef __attribute__((ext_vector_type(8))) short short8;
typedef __attribute__((ext_vector_type(4))) float f32x4;

__device__ __forceinline__ float fsigmoid(float v){ return 1.f/(1.f+__expf(-v)); }
__device__ __forceinline__ float ftanh(float v){ return 2.f/(1.f+__expf(-2.f*v)) - 1.f; }

__device__ __forceinline__ unsigned short f2bf(float f){
  unsigned u = __float_as_uint(f);
  unsigned r = ((u>>16)&1u) + 0x7FFFu;
  return (unsigned short)((u + r)>>16);
}
__device__ __forceinline__ float bf2f(unsigned short s){
  return __uint_as_float(((unsigned)s)<<16);
}
__device__ __forceinline__ void cvt8(const float4& a, const float4& b,
                                     short8& hi, short8& lo){
  float v[8] = {a.x,a.y,a.z,a.w,b.x,b.y,b.z,b.w};
  #pragma unroll
  for (int i=0;i<8;i++){
    unsigned short h = f2bf(v[i]);
    unsigned short l = f2bf(v[i] - bf2f(h));
    ((unsigned short*)&hi)[i] = h;
    ((unsigned short*)&lo)[i] = l;
  }
}

__device__ __forceinline__ void st_agent_f(float* p, float v){
  __hip_atomic_store(p, v, __ATOMIC_RELAXED, __HIP_MEMORY_SCOPE_AGENT);
}
__device__ __forceinline__ void st_agent_u32(unsigned* p, unsigned v){
  __hip_atomic_store(p, v, __ATOMIC_RELAXED, __HIP_MEMORY_SCOPE_AGENT);
}
__device__ __forceinline__ unsigned ldflag(const unsigned* p){
  return __hip_atomic_load(p, __ATOMIC_RELAXED, __HIP_MEMORY_SCOPE_AGENT);
}

__global__ __launch_bounds__(256, 1) void lstm_pers(
    const float* __restrict__ x,    const float* __restrict__ h0in, const float* __restrict__ c0in,
    const float* __restrict__ wih0, const float* __restrict__ whh0,
    const float* __restrict__ bih0, const float* __restrict__ bhh0,
    const float* __restrict__ wih1, const float* __restrict__ whh1,
    const float* __restrict__ bih1, const float* __restrict__ bhh1,
    const float* __restrict__ wlin, const float* __restrict__ blin,
    float* __restrict__ out, float* ws)
{
  __shared__ __align__(16) unsigned short wlds_hi[32768];   // 64 KB
  __shared__ __align__(16) unsigned short wlds_lo[32768];   // 64 KB
  const int tid = threadIdx.x, wg = blockIdx.x;
  const int lane = tid & 63;
  const int wid  = tid >> 6;
  const int mtile = wid >> 1;
  const int ntile = wid & 1;
  const int bgrp = wg & 1;
  const int half = (wg >> 1) & 1;      // 0: layer0, 1: layer1
  const int cg   = wg >> 2;            // 0..63
  const int colbase = cg*8;

  unsigned* flags = (unsigned*)ws;                  // 4 domains x 256 lines
  unsigned* F0 = flags + (bgrp*2 + 0)*4096;
  unsigned* F1 = flags + (bgrp*2 + 1)*4096;
  unsigned* myF = half ? F1 : F0;
  unsigned* rbase = ((unsigned*)ws) + 16384;        // byte 65536
  unsigned* r0h = rbase;                            // [4 slot][2 bgrp][8192]
  unsigned* r0l = rbase + 65536;
  unsigned* r1h = rbase + 131072;
  unsigned* r1l = rbase + 196608;

  // ---- W (bf16 hi/lo) into LDS, ntile-major: c = ((nt*NC+ch)*4+ks)*16+n ----
  if (half == 0){
    for (int c = tid; c < 2560; c += 256){          // NC=20
      int nt = c / 1280; int rem = c - nt*1280;
      int ch = rem >> 6; int ks = (rem>>4)&3; int n = rem & 15;
      int kk = ch*32 + ks*8;
      int wrow = (n>>2)*512 + colbase + nt*4 + (n&3);
      const float* src; long off;
      if (kk < 512){ src = whh0; off = (long)wrow*512 + kk; }
      else         { src = wih0; off = (long)wrow*128 + (kk-512); }
      float4 a = *(const float4*)(src + off);
      float4 b = *(const float4*)(src + off + 4);
      short8 hi, lo; cvt8(a, b, hi, lo);
      *(short8*)(wlds_hi + (size_t)c*8) = hi;
      *(short8*)(wlds_lo + (size_t)c*8) = lo;
    }
  } else {
    for (int c = tid; c < 4096; c += 256){          // NC=32
      int nt = c >> 11; int rem = c & 2047;
      int ch = rem >> 6; int ks = (rem>>4)&3; int n = rem & 15;
      int kk = ch*32 + ks*8;
      int wrow = (n>>2)*512 + colbase + nt*4 + (n&3);
      const float* src; long off;
      if (kk < 512){ src = whh1; off = (long)wrow*512 + kk; }
      else         { src = wih1; off = (long)wrow*512 + (kk-512); }
      float4 a = *(const float4*)(src + off);
      float4 b = *(const float4*)(src + off + 4);
      short8 hi, lo; cvt8(a, b, hi, lo);
      *(short8*)(wlds_hi + (size_t)c*8) = hi;
      *(short8*)(wlds_lo + (size_t)c*8) = lo;
    }
  }

  // ---- per-lane cell state (1 cell/lane after transpose) ----
  const int jpos = (lane>>2)&3;
  const int cc   = lane&3;
  const int col_own = colbase + ntile*4 + cc;
  const int bl_own  = mtile*16 + (lane>>4)*4 + jpos;   // local batch 0..31
  float biasr[4], cst;
  #pragma unroll
  for (int g=0; g<4; ++g){
    biasr[g] = half ? (bih1[g*512+col_own] + bhh1[g*512+col_own])
                    : (bih0[g*512+col_own] + bhh0[g*512+col_own]);
  }
  cst = c0in[half*32768 + (size_t)(bgrp*32+bl_own)*512 + col_own];
  float blin_r = blin[0];
  const int c0p = col_own & ~1;
  const int prodoff = (c0p>>5)*512 + (bl_own>>4)*256
                    + (((bl_own&15) | (((c0p>>3)&3)<<4))<<2) + ((c0p&7)>>1);

  // ---- y-role (L0 group, wave with mtile == cg>>4, ntile 0; cg<32) ----
  float wl[8];
  {
    const float4* wp = (const float4*)wlin + (lane*2);
    float4 w0 = wp[0], w1 = wp[1];
    wl[0]=w0.x; wl[1]=w0.y; wl[2]=w0.z; wl[3]=w0.w;
    wl[4]=w1.x; wl[5]=w1.y; wl[6]=w1.z; wl[7]=w1.w;
  }
  const int yoff = (lane>>2)*512 + ((cg>>4)&1)*256
                 + ((((cg&15) | ((lane&3)<<4)))<<2);

  // ---- init h(-1) into slot 0 (fragment-major), domain-restricted ----
  {
    int e = cg*256 + tid;                  // [0, 16384) in (half,bgrp) slab
    if (!(e & 1)){
      int m = e >> 9;
      int col = e & 511;
      const float* src = h0in + half*32768 + (size_t)(bgrp*32+m)*512 + col;
      float v0 = src[0], v1 = src[1];
      unsigned short hA = f2bf(v0), lA = f2bf(v0 - bf2f(hA));
      unsigned short hB = f2bf(v1), lB = f2bf(v1 - bf2f(hB));
      unsigned uh = (unsigned)hA | ((unsigned)hB<<16);
      unsigned ul = (unsigned)lA | ((unsigned)lB<<16);
      int off = (col>>5)*512 + (m>>4)*256
              + (((m&15) | (((col>>3)&3)<<4))<<2) + ((col&7)>>1);
      unsigned* ph = (half ? r1h : r0h) + (0*2 + bgrp)*8192;
      unsigned* pl = (half ? r1l : r0l) + (0*2 + bgrp)*8192;
      st_agent_u32(ph + off, uh);
      st_agent_u32(pl + off, ul);
    }
  }

  // publish init (per-wave flag = 1) after WG-wide drain + W visible
  asm volatile("s_waitcnt vmcnt(0)" ::: "memory");
  __syncthreads();
  if (lane == 0) st_agent_u32(&myF[(cg*4 + wid)*16], 1u);

  const int kslot = lane >> 4;
  const int nlane = lane & 15;
  const int aoff  = mtile*256 + lane*4;       // + chunk*512, uints
  const size_t xrow = (size_t)(bgrp*32 + mtile*16 + nlane)*65536;

  // mtile-matched flag lines to poll (lane -> producer WG cg'=lane)
  const unsigned* pF0a = F0 + (lane*4 + mtile*2)*16;
  const unsigned* pF0b = pF0a + 16;
  const unsigned* pF1a = F1 + (lane*4 + mtile*2)*16;
  const unsigned* pF1b = pF1a + 16;

  if (half == 0){
    // ================= LAYER-0 WAVES =================
    const bool isy = (cg < 32) && (wid == ((cg>>4)<<1));
    for (int t = 0; t < TT; ++t){
      { // poll: h0(t-1) rows (mtile) ready; backpressure F1>=t-2 (t>=4)
        unsigned need0 = (unsigned)(t+1);
        bool bp = (t >= 4);
        unsigned need1 = (unsigned)(t-2);
        int it = 0;
        for(;;){
          bool ok = (ldflag(pF0a) >= need0) & (ldflag(pF0b) >= need0);
          if (bp) ok &= (ldflag(pF1a) >= need1) & (ldflag(pF1b) >= need1);
          if (__all(ok)) break;
          if (++it > 8) __builtin_amdgcn_s_sleep(1);
        }
      }
      __builtin_amdgcn_fence(__ATOMIC_ACQUIRE, "agent");

      const unsigned* rAh = r0h + ((t&3)*2 + bgrp)*8192;   // h0(t-1)
      const unsigned* rAl = r0l + ((t&3)*2 + bgrp)*8192;
      f32x4 acc = {0.f,0.f,0.f,0.f};
      #pragma unroll
      for (int ch=0; ch<20; ++ch){
        short8 ah, al;
        if (ch >= 16){
          int d = ch*32 + kslot*8 - 512;
          const float* xp = x + xrow + (size_t)t*128 + d;
          float4 u0 = *(const float4*)xp, u1 = *(const float4*)(xp+4);
          cvt8(u0,u1,ah,al);
        } else {
          int o = ch*512 + aoff;
          ah = *(const short8*)(rAh + o);
          al = *(const short8*)(rAl + o);
        }
        int c = ((ntile*20 + ch)*4 + kslot)*16 + nlane;
        short8 wh8 = *(const short8*)(wlds_hi + (size_t)c*8);
        short8 wl8 = *(const short8*)(wlds_lo + (size_t)c*8);
        acc = __builtin_amdgcn_mfma_f32_16x16x32_bf16(ah, wh8, acc, 0,0,0);
        acc = __builtin_amdgcn_mfma_f32_16x16x32_bf16(al, wh8, acc, 0,0,0);
        acc = __builtin_amdgcn_mfma_f32_16x16x32_bf16(ah, wl8, acc, 0,0,0);
      }
      // in-wave 4x4 transpose (lanes ^4, ^8): lane ends with all 4 gates
      float v0=acc[0], v1=acc[1], v2=acc[2], v3=acc[3];
      { bool b0 = (jpos & 1) != 0;
        float s0 = b0 ? v0 : v1, s1 = b0 ? v2 : v3;
        float r0 = __shfl_xor(s0, 4, 64), r1 = __shfl_xor(s1, 4, 64);
        if (b0){ v0=r0; v2=r1; } else { v1=r0; v3=r1; }
      }
      { bool b1 = ((jpos>>1) & 1) != 0;
        float s0 = b1 ? v0 : v2, s1 = b1 ? v1 : v3;
        float r0 = __shfl_xor(s0, 8, 64), r1 = __shfl_xor(s1, 8, 64);
        if (b1){ v0=r0; v1=r1; } else { v2=r0; v3=r1; }
      }
      float gi = fsigmoid(v0 + biasr[0]);
      float gf = fsigmoid(v1 + biasr[1]);
      float gg = ftanh   (v2 + biasr[2]);
      float go = fsigmoid(v3 + biasr[3]);
      float c_ = gf*cst + gi*gg; cst = c_;
      float h = go * ftanh(c_);
      float h_oth = __shfl_xor(h, 1, 64);
      if (!(lane & 1)){
        unsigned short hA = f2bf(h),     lA = f2bf(h - bf2f(hA));
        unsigned short hB = f2bf(h_oth), lB = f2bf(h_oth - bf2f(hB));
        unsigned uh = (unsigned)hA | ((unsigned)hB<<16);
        unsigned ul = (unsigned)lA | ((unsigned)lB<<16);
        int sbase = (((t+1)&3)*2 + bgrp)*8192;
        st_agent_u32(r0h + sbase + prodoff, uh);
        st_agent_u32(r0l + sbase + prodoff, ul);
      }
      // y(t-4) BEFORE flag: L1's overwrite of that slot (its step t) is
      // gated on F0>=t+2 (published below); read data bound by vmcnt(0).
      if (isy && t >= 4){
        int j = t - 4;
        int sbase = (((t-3)&3)*2 + bgrp)*8192;
        uint4 a = *(const uint4*)(r1h + sbase + yoff);
        uint4 b = *(const uint4*)(r1l + sbase + yoff);
        unsigned a4[4] = {a.x,a.y,a.z,a.w}, b4[4] = {b.x,b.y,b.z,b.w};
        float p = 0.f;
        #pragma unroll
        for (int q=0;q<4;q++){
          unsigned qa=a4[q], qb=b4[q];
          float e0 = __uint_as_float(qa<<16) + __uint_as_float(qb<<16);
          float e1 = __uint_as_float(qa & 0xFFFF0000u) + __uint_as_float(qb & 0xFFFF0000u);
          p += e0*wl[2*q] + e1*wl[2*q+1];
        }
        #pragma unroll
        for (int m=1; m<64; m<<=1) p += __shfl_xor(p, m, 64);
        if (lane == 0) st_agent_f(&out[(bgrp*32+cg)*512 + j], p + blin_r);
      }
      asm volatile("s_waitcnt vmcnt(0)" ::: "memory");
      if (lane == 0) st_agent_u32(&F0[(cg*4 + wid)*16], (unsigned)(t+2));
    }
    // epilogue: y(508..511)
    if (isy){
      { unsigned need = (unsigned)(TT+1);
        int it = 0;
        for(;;){
          bool ok = (ldflag(pF1a) >= need) & (ldflag(pF1b) >= need);
          if (__all(ok)) break;
          if (++it > 8) __builtin_amdgcn_s_sleep(1);
        }
      }
      __builtin_amdgcn_fence(__ATOMIC_ACQUIRE, "agent");
      #pragma unroll
      for (int e=0; e<4; ++e){
        int j = TT-4+e;
        int sbase = (((j+1)&3)*2 + bgrp)*8192;
        uint4 a = *(const uint4*)(r1h + sbase + yoff);
        uint4 b = *(const uint4*)(r1l + sbase + yoff);
        unsigned a4[4] = {a.x,a.y,a.z,a.w}, b4[4] = {b.x,b.y,b.z,b.w};
        float p = 0.f;
        #pragma unroll
        for (int q=0;q<4;q++){
          unsigned qa=a4[q], qb=b4[q];
          float e0 = __uint_as_float(qa<<16) + __uint_as_float(qb<<16);
          float e1 = __uint_as_float(qa & 0xFFFF0000u) + __uint_as_float(qb & 0xFFFF0000u);
          p += e0*wl[2*q] + e1*wl[2*q+1];
        }
        #pragma unroll
        for (int m=1; m<64; m<<=1) p += __shfl_xor(p, m, 64);
        if (lane == 0) st_agent_f(&out[(bgrp*32+cg)*512 + j], p + blin_r);
      }
    }
  } else {
    // ================= LAYER-1 WAVES =================
    for (int s = 0; s < TT; ++s){
      { // poll: h1(s-1) rows (F1>=s+1) AND h0(s) rows (F0>=s+2), mtile-matched
        unsigned need1 = (unsigned)(s+1);
        unsigned need0 = (unsigned)(s+2);
        int it = 0;
        for(;;){
          bool ok = (ldflag(pF1a) >= need1) & (ldflag(pF1b) >= need1)
                  & (ldflag(pF0a) >= need0) & (ldflag(pF0b) >= need0);
          if (__all(ok)) break;
          if (++it > 8) __builtin_amdgcn_s_sleep(1);
        }
      }
      __builtin_amdgcn_fence(__ATOMIC_ACQUIRE, "agent");

      const unsigned* rAh = r1h + ((s&3)*2 + bgrp)*8192;      // h1(s-1)
      const unsigned* rAl = r1l + ((s&3)*2 + bgrp)*8192;
      const unsigned* rBh = r0h + (((s+1)&3)*2 + bgrp)*8192;  // h0(s)
      const unsigned* rBl = r0l + (((s+1)&3)*2 + bgrp)*8192;
      f32x4 acc = {0.f,0.f,0.f,0.f};
      #pragma unroll
      for (int ch=0; ch<32; ++ch){
        short8 ah, al;
        if (ch >= 16){
          int o = (ch-16)*512 + aoff;
          ah = *(const short8*)(rBh + o);
          al = *(const short8*)(rBl + o);
        } else {
          int o = ch*512 + aoff;
          ah = *(const short8*)(rAh + o);
          al = *(const short8*)(rAl + o);
        }
        int c = ((ntile*32 + ch)*4 + kslot)*16 + nlane;
        short8 wh8 = *(const short8*)(wlds_hi + (size_t)c*8);
        short8 wl8 = *(const short8*)(wlds_lo + (size_t)c*8);
        acc = __builtin_amdgcn_mfma_f32_16x16x32_bf16(ah, wh8, acc, 0,0,0);
        acc = __builtin_amdgcn_mfma_f32_16x16x32_bf16(al, wh8, acc, 0,0,0);
        acc = __builtin_amdgcn_mfma_f32_16x16x32_bf16(ah, wl8, acc, 0,0,0);
      }
      float v0=acc[0], v1=acc[1], v2=acc[2], v3=acc[3];
      { bool b0 = (jpos & 1) != 0;
        float s0 = b0 ? v0 : v1, s1 = b0 ? v2 : v3;
        float r0 = __shfl_xor(s0, 4, 64), r1 = __shfl_xor(s1, 4, 64);
        if (b0){ v0=r0; v2=r1; } else { v1=r0; v3=r1; }
      }
      { bool b1 = ((jpos>>1) & 1) != 0;
        float s0 = b1 ? v0 : v2, s1 = b1 ? v1 : v3;
        float r0 = __shfl_xor(s0, 8, 64), r1 = __shfl_xor(s1, 8, 64);
        if (b1){ v0=r0; v1=r1; } else { v2=r0; v3=r1; }
      }
      float gi = fsigmoid(v0 + biasr[0]);
      float gf = fsigmoid(v1 + biasr[1]);
      float gg = ftanh   (v2 + biasr[2]);
      float go = fsigmoid(v3 + biasr[3]);
      float c_ = gf*cst + gi*gg; cst = c_;
      float h = go * ftanh(c_);
      float h_oth = __shfl_xor(h, 1, 64);
      if (!(lane & 1)){
        unsigned short hA = f2bf(h),     lA = f2bf(h - bf2f(hA));
        unsigned short hB = f2bf(h_oth), lB = f2bf(h_oth - bf2f(hB));
        unsigned uh = (unsigned)hA | ((unsigned)hB<<16);
        unsigned ul = (unsigned)lA | ((unsigned)lB<<16);
        int sbase = (((s+1)&3)*2 + bgrp)*8192;
        st_agent_u32(r1h + sbase + prodoff, uh);
        st_agent_u32(r1l + sbase + prodoff, ul);
      }
      asm volatile("s_waitcnt vmcnt(0)" ::: "memory");
      if (lane == 0) st_agent_u32(&F1[(cg*4 + wid)*16], (unsigned)(s+2));
    }
  }
}

extern "C" void kernel_launch(void* const* d_in, const int* in_sizes, int n_in,
                              void* d_out, int out_size, void* d_ws, size_t ws_size,
                              hipStream_t stream)
{
  (void)in_sizes; (void)n_in; (void)out_size; (void)ws_size;
  const float* x    = (const float*)d_in[0];
  const float* h0   = (const float*)d_in[1];
  const float* c0   = (const float*)d_in[2];
  const float* wih0 = (const float*)d_in[3];
  const float* whh0 = (const float*)d_in[4];
  const float* bih0 = (const float*)d_in[5];
  const float* bhh0 = (const float*)d_in[6];
  const float* wih1 = (const float*)d_in[7];
  const float* whh1 = (const float*)d_in[8];
  const float* bih1 = (const float*)d_in[9];
  const float* bhh1 = (const float*)d_in[10];
  const float* wlin = (const float*)d_in[11];
  const float* blin = (const float*)d_in[12];
  float* outp = (float*)d_out;
  float* wsp  = (float*)d_ws;

  // zero per-wave flag lines (64KB); rings fully rewritten each launch
  hipMemsetAsync(d_ws, 0, 65536, stream);

  void* args[] = { &x, &h0, &c0, &wih0, &whh0, &bih0, &bhh0,
                   &wih1, &whh1, &bih1, &bhh1, &wlin, &blin, &outp, &wsp };
  hipError_t err = hipLaunchCooperativeKernel((const void*)lstm_pers,
                                              dim3(NWG), dim3(256), args, 0, stream);
  if (err != hipSuccess){
    // Fallback: 1 block/CU (128KB LDS), 256 blocks on 256 CUs -> co-resident.
    hipLaunchKernelGGL(lstm_pers, dim3(NWG), dim3(256), 0, stream,
                       x, h0, c0, wih0, whh0, bih0, bhh0,
                       wih1, whh1, bih1, bhh1, wlin, blin, outp, wsp);
  }
}

// Round 16
// 6637.650 us; speedup vs baseline: 1.1836x; 1.1836x over previous
//
#include <hip/hip_runtime.h>
#include <math.h>

// Persistent cooperative 2-layer LSTM. Round 16: R14 (best, 6.65ms) + BURNER
// WAVES to defeat SMU idle-downclocking. Block = 512 threads: tid<256 = exact
// R14 compute roles; tid>=256 = 4 burner waves spinning independent FMAs
// (no memory traffic, no polls) until an LDS done flag -> CU looks busy ->
// SCLK stays high. In-loop WG barriers become an LDS counter barrier over the
// 4 compute waves (workgroup-scope only, no cache invalidates). Everything
// else byte-identical to R14: fragment-major rings, plain b128 ring reads +
// one agent-acquire fence per step, agent write-through stores, decoupled
// (bgrp,layer) domains, per-WG single-hop flags, dependency-split L1 polls,
// y on L0 side. Split precision MFMA: Whi*hhi + Whi*hlo + Wlo*hhi.
//
// ws layout (bytes): flags[4][64] lines @0 (16KB); uints @20480:
//   r0h[4][2][8192], r0l, r1h, r1l (256KB per plane, 1MB).

#define TT 512
#define NWG 256

typedef __attribute__((ext_vector_type(8))) short short8;
typedef __attribute__((ext_vector_type(4))) float f32x4;

#define RED(K,M,N) ((((K)*32+(M))*35)+(N))
#define RED_TOT (2*32*35)

__device__ __forceinline__ float fsigmoid(float v){ return 1.f/(1.f+__expf(-v)); }
__device__ __forceinline__ float ftanh(float v){ return 2.f/(1.f+__expf(-2.f*v)) - 1.f; }

__device__ __forceinline__ unsigned short f2bf(float f){
  unsigned u = __float_as_uint(f);
  unsigned r = ((u>>16)&1u) + 0x7FFFu;
  return (unsigned short)((u + r)>>16);
}
__device__ __forceinline__ float bf2f(unsigned short s){
  return __uint_as_float(((unsigned)s)<<16);
}
__device__ __forceinline__ void cvt8(const float4& a, const float4& b,
                                     short8& hi, short8& lo){
  float v[8] = {a.x,a.y,a.z,a.w,b.x,b.y,b.z,b.w};
  #pragma unroll
  for (int i=0;i<8;i++){
    unsigned short h = f2bf(v[i]);
    unsigned short l = f2bf(v[i] - bf2f(h));
    ((unsigned short*)&hi)[i] = h;
    ((unsigned short*)&lo)[i] = l;
  }
}

__device__ __forceinline__ void st_agent_f(float* p, float v){
  __hip_atomic_store(p, v, __ATOMIC_RELAXED, __HIP_MEMORY_SCOPE_AGENT);
}
__device__ __forceinline__ void st_agent_u32(unsigned* p, unsigned v){
  __hip_atomic_store(p, v, __ATOMIC_RELAXED, __HIP_MEMORY_SCOPE_AGENT);
}
__device__ __forceinline__ unsigned ldflag(const unsigned* p){
  return __hip_atomic_load(p, __ATOMIC_RELAXED, __HIP_MEMORY_SCOPE_AGENT);
}

// LDS barrier over the 4 COMPUTE waves only (burners excluded). Monotonic
// counter; workgroup-scope fences lower to lgkmcnt waits (no cache inv).
__device__ __forceinline__ void cbar(unsigned* ctr, unsigned target, int tid){
  __builtin_amdgcn_fence(__ATOMIC_RELEASE, "workgroup");
  if ((tid & 63) == 0) atomicAdd(ctr, 1u);
  while (__hip_atomic_load(ctr, __ATOMIC_RELAXED, __HIP_MEMORY_SCOPE_WORKGROUP) < target) {}
  __builtin_amdgcn_fence(__ATOMIC_ACQUIRE, "workgroup");
}

// Per-wave poll: lane l polls flag line l of a 64-flag domain.
__device__ __forceinline__ void pollwave(const unsigned* F, unsigned need, int lane){
  int it = 0;
  for(;;){
    bool ok = ldflag(&F[lane*16]) >= need;
    if (__all(ok)) break;
    if (++it > 8) __builtin_amdgcn_s_sleep(1);
  }
}
__device__ __forceinline__ void pollwave2(const unsigned* Fa, unsigned na,
                                          const unsigned* Fb, unsigned nb,
                                          bool useb, int lane){
  int it = 0;
  for(;;){
    bool ok = ldflag(&Fa[lane*16]) >= na;
    if (useb) ok &= (ldflag(&Fb[lane*16]) >= nb);
    if (__all(ok)) break;
    if (++it > 8) __builtin_amdgcn_s_sleep(1);
  }
}

// Gate MFMA loop (R13/R14). A-frags: PLAIN coalesced short8 loads from
// fragment-major ring slabs (lane-dense: slab + (chunk*2+sub)*256 + lane*4).
template<int KFC, int LAYER, int KHALF>
__device__ __forceinline__ void gates_mfma(
    const unsigned* __restrict__ rAh, const unsigned* __restrict__ rAl,
    const unsigned* __restrict__ rBh, const unsigned* __restrict__ rBl,
    const unsigned* xsh_t, const unsigned* xsl_t,
    const unsigned short* wh, const unsigned short* wlo,
    int lane, int m0loc, int kslot, int nidx,
    f32x4& acc0, f32x4& acc1)
{
  #pragma unroll
  for (int kf=0; kf<KFC; ++kf){
    short8 a0h,a0l,a1h,a1l;
    if (LAYER==0 && KHALF==1 && kf>=6){
      int d2 = (kf-6)*16 + kslot*4;          // uint offset within x row
      a0h = *(const short8*)(xsh_t + m0loc*68 + d2);
      a0l = *(const short8*)(xsl_t + m0loc*68 + d2);
      a1h = *(const short8*)(xsh_t + (m0loc+16)*68 + d2);
      a1l = *(const short8*)(xsl_t + (m0loc+16)*68 + d2);
    } else {
      constexpr int CB = LAYER ? 0 : (KHALF*10);
      const unsigned *bh, *bl;
      int chunk;
      if (LAYER==1 && KHALF==1){ bh = rBh; bl = rBl; chunk = kf; }
      else                     { bh = rAh; bl = rAl; chunk = CB + kf; }
      int o0 = chunk*512 + lane*4;           // sub 0 (rows 0..15)
      a0h = *(const short8*)(bh + o0);
      a0l = *(const short8*)(bl + o0);
      a1h = *(const short8*)(bh + o0 + 256); // sub 1 (rows 16..31)
      a1l = *(const short8*)(bl + o0 + 256);
    }
    int c = ((KHALF*KFC + kf)*4 + kslot)*32 + nidx;
    short8 bhW = *(const short8*)(wh  + (size_t)c*8);
    short8 blW = *(const short8*)(wlo + (size_t)c*8);
    acc0 = __builtin_amdgcn_mfma_f32_16x16x32_bf16(a0h, bhW, acc0, 0,0,0);
    acc0 = __builtin_amdgcn_mfma_f32_16x16x32_bf16(a0l, bhW, acc0, 0,0,0);
    acc0 = __builtin_amdgcn_mfma_f32_16x16x32_bf16(a0h, blW, acc0, 0,0,0);
    acc1 = __builtin_amdgcn_mfma_f32_16x16x32_bf16(a1h, bhW, acc1, 0,0,0);
    acc1 = __builtin_amdgcn_mfma_f32_16x16x32_bf16(a1l, bhW, acc1, 0,0,0);
    acc1 = __builtin_amdgcn_mfma_f32_16x16x32_bf16(a1h, blW, acc1, 0,0,0);
  }
}

__global__ __launch_bounds__(512, 1) void lstm_pers(
    const float* __restrict__ x,    const float* __restrict__ h0in, const float* __restrict__ c0in,
    const float* __restrict__ wih0, const float* __restrict__ whh0,
    const float* __restrict__ bih0, const float* __restrict__ bhh0,
    const float* __restrict__ wih1, const float* __restrict__ whh1,
    const float* __restrict__ bih1, const float* __restrict__ bhh1,
    const float* __restrict__ wlin, const float* __restrict__ blin,
    float* __restrict__ out, float* ws)
{
  __shared__ __align__(16) unsigned short wlds_hi[32768];   // 65,536 B
  __shared__ __align__(16) unsigned short wlds_lo[32768];   // 65,536 B
  __shared__ __align__(16) float red[RED_TOT];              //  8,960 B
  __shared__ unsigned ctrl[16];                             // [0]=bar, [8]=done
  const int tid = threadIdx.x, wg = blockIdx.x;
  const int lane = tid & 63;
  const int wid  = tid >> 6;
  const int bgrp = wg & 1;
  const int half = (wg >> 1) & 1;      // 0: layer0, 1: layer1
  const int cg   = wg >> 2;            // 0..63
  const int colbase = cg*8;
  const int khalf = wid & 1;
  const int ntile = wid >> 1;

  unsigned* flags = (unsigned*)ws;                  // 4 domains x 64 lines
  unsigned* F0 = flags + (bgrp*2 + 0)*1024;
  unsigned* F1 = flags + (bgrp*2 + 1)*1024;
  unsigned* myF = half ? F1 : F0;
  unsigned* r0h = ((unsigned*)ws) + 5120;           // planes: [4 slot][2 bgrp][8192]
  unsigned* r0l = r0h + 65536;
  unsigned* r1h = r0h + 131072;
  unsigned* r1l = r0h + 196608;

  unsigned* xsh_s = (unsigned*)(wlds_hi + 20480);   // L0 WGs only (overlay)
  unsigned* xsl_s = (unsigned*)(wlds_lo + 20480);

  if (tid == 0){ ctrl[0] = 0; ctrl[8] = 0; }

  // ---- init (compute threads only) ----
  if (tid < 256){
    // W (bf16 hi/lo) into LDS, once
    if (half == 0){
      for (int c = tid; c < 2560; c += 256){
        int kh = c / 1280; int rem = c - kh*1280;
        int kf = rem >> 7; int rem2 = rem & 127;
        int ks = rem2 >> 5; int n = rem2 & 31;
        int kk = kh*320 + kf*32 + ks*8;
        int wrow = (n>>3)*512 + colbase + (n&7);
        const float* src; long off;
        if (kk < 512){ src = whh0; off = (long)wrow*512 + kk; }
        else         { src = wih0; off = (long)wrow*128 + (kk-512); }
        float4 a = *(const float4*)(src + off);
        float4 b = *(const float4*)(src + off + 4);
        short8 hi, lo; cvt8(a, b, hi, lo);
        *(short8*)(wlds_hi + (size_t)c*8) = hi;
        *(short8*)(wlds_lo + (size_t)c*8) = lo;
      }
    } else {
      for (int c = tid; c < 4096; c += 256){
        int kh = c >> 11; int rem = c & 2047;
        int kf = rem >> 7; int rem2 = rem & 127;
        int ks = rem2 >> 5; int n = rem2 & 31;
        int kk = kh*512 + kf*32 + ks*8;
        int wrow = (n>>3)*512 + colbase + (n&7);
        const float* src; long off;
        if (kk < 512){ src = whh1; off = (long)wrow*512 + kk; }
        else         { src = wih1; off = (long)wrow*512 + (kk-512); }
        float4 a = *(const float4*)(src + off);
        float4 b = *(const float4*)(src + off + 4);
        short8 hi, lo; cvt8(a, b, hi, lo);
        *(short8*)(wlds_hi + (size_t)c*8) = hi;
        *(short8*)(wlds_lo + (size_t)c*8) = lo;
      }
    }
    // init h(-1) into slot 0 (fragment-major), domain-restricted
    {
      int e = cg*256 + tid;                  // [0, 16384) in (half,bgrp) slab
      if (!(e & 1)){
        int m = e >> 9;
        int col = e & 511;
        const float* src = h0in + half*32768 + (size_t)(bgrp*32+m)*512 + col;
        float v0 = src[0], v1 = src[1];
        unsigned short hA = f2bf(v0), lA = f2bf(v0 - bf2f(hA));
        unsigned short hB = f2bf(v1), lB = f2bf(v1 - bf2f(hB));
        unsigned uh = (unsigned)hA | ((unsigned)hB<<16);
        unsigned ul = (unsigned)lA | ((unsigned)lB<<16);
        int off = (col>>5)*512 + (m>>4)*256
                + (((m&15) | (((col>>3)&3)<<4))<<2) + ((col&7)>>1);
        unsigned* ph = (half ? r1h : r0h) + (0*2 + bgrp)*8192;
        unsigned* pl = (half ? r1l : r0l) + (0*2 + bgrp)*8192;
        st_agent_u32(ph + off, uh);
        st_agent_u32(pl + off, ul);
      }
    }
    // x stage for t=0 (L0 WGs)
    if (half == 0){
      int m = tid>>3, dd = (tid&7)*16;
      const float* xp = x + ((size_t)(bgrp*32+m))*65536 + 0*128 + dd;
      float4 v0 = *(const float4*)xp,      v1 = *(const float4*)(xp+4),
             v2 = *(const float4*)(xp+8),  v3 = *(const float4*)(xp+12);
      float vv[16] = {v0.x,v0.y,v0.z,v0.w, v1.x,v1.y,v1.z,v1.w,
                      v2.x,v2.y,v2.z,v2.w, v3.x,v3.y,v3.z,v3.w};
      unsigned uh[8], ul[8];
      #pragma unroll
      for (int j=0;j<8;j++){
        unsigned short hA = f2bf(vv[2*j]),   hB = f2bf(vv[2*j+1]);
        unsigned short lA = f2bf(vv[2*j]-bf2f(hA)), lB = f2bf(vv[2*j+1]-bf2f(hB));
        uh[j] = (unsigned)hA | ((unsigned)hB<<16);
        ul[j] = (unsigned)lA | ((unsigned)lB<<16);
      }
      unsigned* dh = xsh_s + m*68 + (dd>>1);
      unsigned* dl = xsl_s + m*68 + (dd>>1);
      *(uint4*)dh     = make_uint4(uh[0],uh[1],uh[2],uh[3]);
      *(uint4*)(dh+4) = make_uint4(uh[4],uh[5],uh[6],uh[7]);
      *(uint4*)dl     = make_uint4(ul[0],ul[1],ul[2],ul[3]);
      *(uint4*)(dl+4) = make_uint4(ul[4],ul[5],ul[6],ul[7]);
    }
  }

  // ---- per-thread state (compute roles; harmless for burners) ----
  const int m_l = (tid & 255) >> 3;
  const int cl  = tid & 7;
  const int col_own = colbase + cl;
  float biasr[4], cst;
  #pragma unroll
  for (int g=0; g<4; ++g){
    biasr[g] = half ? (bih1[g*512+col_own] + bhh1[g*512+col_own])
                    : (bih0[g*512+col_own] + bhh0[g*512+col_own]);
  }
  cst = c0in[half*32768 + (size_t)(bgrp*32+m_l)*512 + col_own];
  float blin_r = blin[0];
  const int c0p   = col_own & ~1;
  const int prodoff = (c0p>>5)*512 + (m_l>>4)*256
                    + (((m_l&15) | (((c0p>>3)&3)<<4))<<2) + ((c0p&7)>>1);

  float wl[8];
  {
    const float4* wp = (const float4*)wlin + (lane*2);
    float4 w0 = wp[0], w1 = wp[1];
    wl[0]=w0.x; wl[1]=w0.y; wl[2]=w0.z; wl[3]=w0.w;
    wl[4]=w1.x; wl[5]=w1.y; wl[6]=w1.z; wl[7]=w1.w;
  }
  const int yoff = (lane>>2)*512 + ((cg>>4)&1)*256
                 + ((((cg&15) | ((lane&3)<<4)))<<2);

  asm volatile("s_waitcnt vmcnt(0)" ::: "memory");
  __syncthreads();                       // all 512 threads, once
  if (tid == 0) st_agent_u32(&myF[cg*16], 1u);

  // ================== BURNER WAVES ==================
  if (tid >= 256){
    float a0=1e-30f, a1=1.00001e-30f, a2=1.00002e-30f, a3=1.00003e-30f;
    for(;;){
      if (__hip_atomic_load(&ctrl[8], __ATOMIC_RELAXED, __HIP_MEMORY_SCOPE_WORKGROUP)) break;
      #pragma unroll
      for (int i=0;i<16;i++){
        asm volatile("v_fmac_f32 %0,%1,%2":"+v"(a0):"v"(a1),"v"(a2));
        asm volatile("v_fmac_f32 %0,%1,%2":"+v"(a1):"v"(a2),"v"(a3));
        asm volatile("v_fmac_f32 %0,%1,%2":"+v"(a2):"v"(a3),"v"(a0));
        asm volatile("v_fmac_f32 %0,%1,%2":"+v"(a3):"v"(a0),"v"(a1));
      }
    }
    asm volatile("" :: "v"(a0),"v"(a1),"v"(a2),"v"(a3));
    return;
  }

  // ================== COMPUTE WAVES (exact R14) ==================
  const int m0loc = lane & 15;
  const int kslot = lane >> 4;
  const int nidx  = ntile*16 + (lane & 15);
  unsigned barph = 0;

  if (half == 0){
    // ---------- LAYER-0 GROUP ----------
    for (int t = 0; t < TT; ++t){
      pollwave2(F0, (unsigned)(t+1), F1, (unsigned)(t-2), t>=4, lane);
      __builtin_amdgcn_fence(__ATOMIC_ACQUIRE, "agent");
      barph += 4; cbar(&ctrl[0], barph, tid);   // orders prev-iter x-stage

      const unsigned* rAh = r0h + ((t&3)*2 + bgrp)*8192;  // h0(t-1)
      const unsigned* rAl = r0l + ((t&3)*2 + bgrp)*8192;
      const unsigned* xsh_t = xsh_s + (t&1)*2176;
      const unsigned* xsl_t = xsl_s + (t&1)*2176;
      f32x4 acc0 = {0.f,0.f,0.f,0.f}, acc1 = {0.f,0.f,0.f,0.f};
      if (khalf == 0) gates_mfma<10,0,0>(rAh,rAl,0,0,xsh_t,xsl_t,wlds_hi,wlds_lo,lane,m0loc,kslot,nidx,acc0,acc1);
      else            gates_mfma<10,0,1>(rAh,rAl,0,0,xsh_t,xsl_t,wlds_hi,wlds_lo,lane,m0loc,kslot,nidx,acc0,acc1);
      #pragma unroll
      for (int r=0; r<4; ++r){
        int mm = kslot*4 + r;
        red[RED(khalf, mm,    nidx)] = acc0[r];
        red[RED(khalf, 16+mm, nidx)] = acc1[r];
      }
      barph += 4; cbar(&ctrl[0], barph, tid);

      {
        float g4[4];
        #pragma unroll
        for (int g=0; g<4; ++g){
          int n = g*8 + cl;
          g4[g] = red[RED(0,m_l,n)] + red[RED(1,m_l,n)] + biasr[g];
        }
        float gi = fsigmoid(g4[0]);
        float gf = fsigmoid(g4[1]);
        float gg = ftanh   (g4[2]);
        float go = fsigmoid(g4[3]);
        float c = gf*cst + gi*gg;
        cst = c;
        float h = go * ftanh(c);
        float h_oth = __shfl_xor(h, 1, 64);
        if (!(tid & 1)){
          unsigned short hA = f2bf(h),     lA = f2bf(h - bf2f(hA));
          unsigned short hB = f2bf(h_oth), lB = f2bf(h_oth - bf2f(hB));
          unsigned uh = (unsigned)hA | ((unsigned)hB<<16);
          unsigned ul = (unsigned)lA | ((unsigned)lB<<16);
          int sbase = (((t+1)&3)*2 + bgrp)*8192;
          st_agent_u32(r0h + sbase + prodoff, uh);
          st_agent_u32(r0l + sbase + prodoff, ul);
        }
      }

      // y(t-4) BEFORE flag store (race-free per R14 proof)
      if (t >= 4 && cg < 32 && wid == 0){
        int j = t - 4;
        int sbase = (((j+1)&3)*2 + bgrp)*8192;
        uint4 a = *(const uint4*)(r1h + sbase + yoff);
        uint4 b = *(const uint4*)(r1l + sbase + yoff);
        unsigned a4[4] = {a.x,a.y,a.z,a.w}, b4[4] = {b.x,b.y,b.z,b.w};
        float p = 0.f;
        #pragma unroll
        for (int q=0;q<4;q++){
          unsigned qa=a4[q], qb=b4[q];
          float e0 = __uint_as_float(qa<<16) + __uint_as_float(qb<<16);
          float e1 = __uint_as_float(qa & 0xFFFF0000u) + __uint_as_float(qb & 0xFFFF0000u);
          p += e0*wl[2*q] + e1*wl[2*q+1];
        }
        #pragma unroll
        for (int m=1; m<64; m<<=1) p += __shfl_xor(p, m, 64);
        if (lane == 0) st_agent_f(&out[(bgrp*32+cg)*512 + j], p + blin_r);
      }

      asm volatile("s_waitcnt vmcnt(0)" ::: "memory");
      barph += 4; cbar(&ctrl[0], barph, tid);
      if (tid == 0) st_agent_u32(&F0[cg*16], (unsigned)(t+2));

      if (t+1 < TT){
        int m = tid>>3, dd = (tid&7)*16;
        const float* xp = x + ((size_t)(bgrp*32+m))*65536 + (size_t)(t+1)*128 + dd;
        float4 v0 = *(const float4*)xp,      v1 = *(const float4*)(xp+4),
               v2 = *(const float4*)(xp+8),  v3 = *(const float4*)(xp+12);
        float vv[16] = {v0.x,v0.y,v0.z,v0.w, v1.x,v1.y,v1.z,v1.w,
                        v2.x,v2.y,v2.z,v2.w, v3.x,v3.y,v3.z,v3.w};
        unsigned uh[8], ul[8];
        #pragma unroll
        for (int j=0;j<8;j++){
          unsigned short hA = f2bf(vv[2*j]),   hB = f2bf(vv[2*j+1]);
          unsigned short lA = f2bf(vv[2*j]-bf2f(hA)), lB = f2bf(vv[2*j+1]-bf2f(hB));
          uh[j] = (unsigned)hA | ((unsigned)hB<<16);
          ul[j] = (unsigned)lA | ((unsigned)lB<<16);
        }
        unsigned* dh = xsh_s + ((t+1)&1)*2176 + m*68 + (dd>>1);
        unsigned* dl = xsl_s + ((t+1)&1)*2176 + m*68 + (dd>>1);
        *(uint4*)dh     = make_uint4(uh[0],uh[1],uh[2],uh[3]);
        *(uint4*)(dh+4) = make_uint4(uh[4],uh[5],uh[6],uh[7]);
        *(uint4*)dl     = make_uint4(ul[0],ul[1],ul[2],ul[3]);
        *(uint4*)(dl+4) = make_uint4(ul[4],ul[5],ul[6],ul[7]);
      }
    }

    // epilogue: y(508..511)
    if (cg < 32 && wid == 0){
      pollwave(F1, (unsigned)(TT+1), lane);
      __builtin_amdgcn_fence(__ATOMIC_ACQUIRE, "agent");
      #pragma unroll
      for (int e=0; e<4; ++e){
        int j = TT-4+e;
        int sbase = (((j+1)&3)*2 + bgrp)*8192;
        uint4 a = *(const uint4*)(r1h + sbase + yoff);
        uint4 b = *(const uint4*)(r1l + sbase + yoff);
        unsigned a4[4] = {a.x,a.y,a.z,a.w}, b4[4] = {b.x,b.y,b.z,b.w};
        float p = 0.f;
        #pragma unroll
        for (int q=0;q<4;q++){
          unsigned qa=a4[q], qb=b4[q];
          float e0 = __uint_as_float(qa<<16) + __uint_as_float(qb<<16);
          float e1 = __uint_as_float(qa & 0xFFFF0000u) + __uint_as_float(qb & 0xFFFF0000u);
          p += e0*wl[2*q] + e1*wl[2*q+1];
        }
        #pragma unroll
        for (int m=1; m<64; m<<=1) p += __shfl_xor(p, m, 64);
        if (lane == 0) st_agent_f(&out[(bgrp*32+cg)*512 + j], p + blin_r);
      }
    }
  } else {
    // ---------- LAYER-1 GROUP: pure recurrence ----------
    for (int s = 0; s < TT; ++s){
      if (khalf == 1) pollwave(F0, (unsigned)(s+2), lane);
      else            pollwave(F1, (unsigned)(s+1), lane);
      __builtin_amdgcn_fence(__ATOMIC_ACQUIRE, "agent");

      const unsigned* rAh = r1h + ((s&3)*2 + bgrp)*8192;      // h1(s-1)
      const unsigned* rAl = r1l + ((s&3)*2 + bgrp)*8192;
      const unsigned* rBh = r0h + (((s+1)&3)*2 + bgrp)*8192;  // h0(s)
      const unsigned* rBl = r0l + (((s+1)&3)*2 + bgrp)*8192;
      f32x4 acc0 = {0.f,0.f,0.f,0.f}, acc1 = {0.f,0.f,0.f,0.f};
      if (khalf == 0) gates_mfma<16,1,0>(rAh,rAl,rBh,rBl,0,0,wlds_hi,wlds_lo,lane,m0loc,kslot,nidx,acc0,acc1);
      else            gates_mfma<16,1,1>(rAh,rAl,rBh,rBl,0,0,wlds_hi,wlds_lo,lane,m0loc,kslot,nidx,acc0,acc1);
      #pragma unroll
      for (int r=0; r<4; ++r){
        int mm = kslot*4 + r;
        red[RED(khalf, mm,    nidx)] = acc0[r];
        red[RED(khalf, 16+mm, nidx)] = acc1[r];
      }
      barph += 4; cbar(&ctrl[0], barph, tid);   // sync1: joins split waves

      {
        float g4[4];
        #pragma unroll
        for (int g=0; g<4; ++g){
          int n = g*8 + cl;
          g4[g] = red[RED(0,m_l,n)] + red[RED(1,m_l,n)] + biasr[g];
        }
        float gi = fsigmoid(g4[0]);
        float gf = fsigmoid(g4[1]);
        float gg = ftanh   (g4[2]);
        float go = fsigmoid(g4[3]);
        float c = gf*cst + gi*gg;
        cst = c;
        float h = go * ftanh(c);
        float h_oth = __shfl_xor(h, 1, 64);
        if (!(tid & 1)){
          unsigned short hA = f2bf(h),     lA = f2bf(h - bf2f(hA));
          unsigned short hB = f2bf(h_oth), lB = f2bf(h_oth - bf2f(hB));
          unsigned uh = (unsigned)hA | ((unsigned)hB<<16);
          unsigned ul = (unsigned)lA | ((unsigned)lB<<16);
          int sbase = (((s+1)&3)*2 + bgrp)*8192;
          st_agent_u32(r1h + sbase + prodoff, uh);
          st_agent_u32(r1l + sbase + prodoff, ul);
        }
      }
      asm volatile("s_waitcnt vmcnt(0)" ::: "memory");
      barph += 4; cbar(&ctrl[0], barph, tid);   // sync2
      if (tid == 0) st_agent_u32(&F1[cg*16], (unsigned)(s+2));
    }
  }

  // stop burners
  if (tid == 0)
    __hip_atomic_store(&ctrl[8], 1u, __ATOMIC_RELEASE, __HIP_MEMORY_SCOPE_WORKGROUP);
}

extern "C" void kernel_launch(void* const* d_in, const int* in_sizes, int n_in,
                              void* d_out, int out_size, void* d_ws, size_t ws_size,
                              hipStream_t stream)
{
  (void)in_sizes; (void)n_in; (void)out_size; (void)ws_size;
  const float* x    = (const float*)d_in[0];
  const float* h0   = (const float*)d_in[1];
  const float* c0   = (const float*)d_in[2];
  const float* wih0 = (const float*)d_in[3];
  const float* whh0 = (const float*)d_in[4];
  const float* bih0 = (const float*)d_in[5];
  const float* bhh0 = (const float*)d_in[6];
  const float* wih1 = (const float*)d_in[7];
  const float* whh1 = (const float*)d_in[8];
  const float* bih1 = (const float*)d_in[9];
  const float* bhh1 = (const float*)d_in[10];
  const float* wlin = (const float*)d_in[11];
  const float* blin = (const float*)d_in[12];
  float* outp = (float*)d_out;
  float* wsp  = (float*)d_ws;

  hipMemsetAsync(d_ws, 0, 18432, stream);

  void* args[] = { &x, &h0, &c0, &wih0, &whh0, &bih0, &bhh0,
                   &wih1, &whh1, &bih1, &bhh1, &wlin, &blin, &outp, &wsp };
  hipError_t err = hipLaunchCooperativeKernel((const void*)lstm_pers,
                                              dim3(NWG), dim3(512), args, 0, stream);
  if (err != hipSuccess){
    // Fallback: 1 block/CU (140KB LDS), 256 blocks on 256 CUs -> co-resident.
    hipLaunchKernelGGL(lstm_pers, dim3(NWG), dim3(512), 0, stream,
                       x, h0, c0, wih0, whh0, bih0, bhh0,
                       wih1, whh1, bih1, bhh1, wlin, blin, outp, wsp);
  }
}

// Round 17
// 3774.512 us; speedup vs baseline: 2.0815x; 1.7585x over previous
//
#include <hip/hip_runtime.h>
#include <math.h>

// Persistent cooperative 2-layer LSTM. Round 17: R16 (R14+burners, 6.64ms)
// MINUS the per-step agent-acquire fence. Ring reads = coalesced 64-bit
// relaxed AGENT-scope atomic loads (L3-served, per-access coherent; proven
// R10-R12) at R13's fragment-major offsets. No buffer_inv per step -> x and
// other read-only data stay L2-resident (FETCH should drop), and the fence
// leaves the L1 critical chain. Producer protocol unchanged: agent
// write-through stores + s_waitcnt vmcnt(0) BEFORE flag store => flag
// observed implies data at L3; atomic loads read L3 directly.
// Everything else byte-identical to R16: burner waves (tid>=256) keep SCLK
// up; LDS cbar for compute waves; decoupled (bgrp,layer) domains; per-WG
// single-hop flags; dependency-split L1 polls; y on L0 side (race-free per
// R14 proof). Split precision MFMA: Whi*hhi + Whi*hlo + Wlo*hhi.
//
// ws layout (bytes): flags[4][64] lines @0 (16KB); uints @20480:
//   r0h[4][2][8192], r0l, r1h, r1l (256KB per plane, 1MB).

#define TT 512
#define NWG 256

typedef __attribute__((ext_vector_type(8))) short short8;
typedef __attribute__((ext_vector_type(4))) float f32x4;

#define RED(K,M,N) ((((K)*32+(M))*35)+(N))
#define RED_TOT (2*32*35)

__device__ __forceinline__ float fsigmoid(float v){ return 1.f/(1.f+__expf(-v)); }
__device__ __forceinline__ float ftanh(float v){ return 2.f/(1.f+__expf(-2.f*v)) - 1.f; }

__device__ __forceinline__ unsigned short f2bf(float f){
  unsigned u = __float_as_uint(f);
  unsigned r = ((u>>16)&1u) + 0x7FFFu;
  return (unsigned short)((u + r)>>16);
}
__device__ __forceinline__ float bf2f(unsigned short s){
  return __uint_as_float(((unsigned)s)<<16);
}
__device__ __forceinline__ void cvt8(const float4& a, const float4& b,
                                     short8& hi, short8& lo){
  float v[8] = {a.x,a.y,a.z,a.w,b.x,b.y,b.z,b.w};
  #pragma unroll
  for (int i=0;i<8;i++){
    unsigned short h = f2bf(v[i]);
    unsigned short l = f2bf(v[i] - bf2f(h));
    ((unsigned short*)&hi)[i] = h;
    ((unsigned short*)&lo)[i] = l;
  }
}

__device__ __forceinline__ void st_agent_f(float* p, float v){
  __hip_atomic_store(p, v, __ATOMIC_RELAXED, __HIP_MEMORY_SCOPE_AGENT);
}
__device__ __forceinline__ void st_agent_u32(unsigned* p, unsigned v){
  __hip_atomic_store(p, v, __ATOMIC_RELAXED, __HIP_MEMORY_SCOPE_AGENT);
}
__device__ __forceinline__ unsigned ldflag(const unsigned* p){
  return __hip_atomic_load(p, __ATOMIC_RELAXED, __HIP_MEMORY_SCOPE_AGENT);
}

// Coherent 16B ring read at a COALESCED (lane-dense) offset: two 64-bit
// relaxed agent atomic loads, served at L3 (bypass L1/L2) - proven R10-R12.
__device__ __forceinline__ short8 ld_ring16(const unsigned* p){
  const unsigned long long* q = (const unsigned long long*)p;
  union { unsigned long long u[2]; short8 s; } v;
  v.u[0] = __hip_atomic_load(&q[0], __ATOMIC_RELAXED, __HIP_MEMORY_SCOPE_AGENT);
  v.u[1] = __hip_atomic_load(&q[1], __ATOMIC_RELAXED, __HIP_MEMORY_SCOPE_AGENT);
  return v.s;
}
__device__ __forceinline__ void ld_ring16_u(const unsigned* p, unsigned o[4]){
  const unsigned long long* q = (const unsigned long long*)p;
  unsigned long long a = __hip_atomic_load(&q[0], __ATOMIC_RELAXED, __HIP_MEMORY_SCOPE_AGENT);
  unsigned long long b = __hip_atomic_load(&q[1], __ATOMIC_RELAXED, __HIP_MEMORY_SCOPE_AGENT);
  o[0] = (unsigned)a; o[1] = (unsigned)(a>>32);
  o[2] = (unsigned)b; o[3] = (unsigned)(b>>32);
}

// LDS barrier over the 4 COMPUTE waves only (burners excluded).
__device__ __forceinline__ void cbar(unsigned* ctr, unsigned target, int tid){
  __builtin_amdgcn_fence(__ATOMIC_RELEASE, "workgroup");
  if ((tid & 63) == 0) atomicAdd(ctr, 1u);
  while (__hip_atomic_load(ctr, __ATOMIC_RELAXED, __HIP_MEMORY_SCOPE_WORKGROUP) < target) {}
  __builtin_amdgcn_fence(__ATOMIC_ACQUIRE, "workgroup");
}

// Per-wave poll: lane l polls flag line l of a 64-flag domain.
__device__ __forceinline__ void pollwave(const unsigned* F, unsigned need, int lane){
  int it = 0;
  for(;;){
    bool ok = ldflag(&F[lane*16]) >= need;
    if (__all(ok)) break;
    if (++it > 8) __builtin_amdgcn_s_sleep(1);
  }
}
__device__ __forceinline__ void pollwave2(const unsigned* Fa, unsigned na,
                                          const unsigned* Fb, unsigned nb,
                                          bool useb, int lane){
  int it = 0;
  for(;;){
    bool ok = ldflag(&Fa[lane*16]) >= na;
    if (useb) ok &= (ldflag(&Fb[lane*16]) >= nb);
    if (__all(ok)) break;
    if (++it > 8) __builtin_amdgcn_s_sleep(1);
  }
}

// Gate MFMA loop. Ring A-frags via coalesced agent atomic loads from
// fragment-major slabs (slab + chunk*512 + lane*4 uints); x via LDS stage.
template<int KFC, int LAYER, int KHALF>
__device__ __forceinline__ void gates_mfma(
    const unsigned* __restrict__ rAh, const unsigned* __restrict__ rAl,
    const unsigned* __restrict__ rBh, const unsigned* __restrict__ rBl,
    const unsigned* xsh_t, const unsigned* xsl_t,
    const unsigned short* wh, const unsigned short* wlo,
    int lane, int m0loc, int kslot, int nidx,
    f32x4& acc0, f32x4& acc1)
{
  #pragma unroll
  for (int kf=0; kf<KFC; ++kf){
    short8 a0h,a0l,a1h,a1l;
    if (LAYER==0 && KHALF==1 && kf>=6){
      int d2 = (kf-6)*16 + kslot*4;          // uint offset within x row
      a0h = *(const short8*)(xsh_t + m0loc*68 + d2);
      a0l = *(const short8*)(xsl_t + m0loc*68 + d2);
      a1h = *(const short8*)(xsh_t + (m0loc+16)*68 + d2);
      a1l = *(const short8*)(xsl_t + (m0loc+16)*68 + d2);
    } else {
      constexpr int CB = LAYER ? 0 : (KHALF*10);
      const unsigned *bh, *bl;
      int chunk;
      if (LAYER==1 && KHALF==1){ bh = rBh; bl = rBl; chunk = kf; }
      else                     { bh = rAh; bl = rAl; chunk = CB + kf; }
      int o0 = chunk*512 + lane*4;           // sub 0 (rows 0..15)
      a0h = ld_ring16(bh + o0);
      a0l = ld_ring16(bl + o0);
      a1h = ld_ring16(bh + o0 + 256);        // sub 1 (rows 16..31)
      a1l = ld_ring16(bl + o0 + 256);
    }
    int c = ((KHALF*KFC + kf)*4 + kslot)*32 + nidx;
    short8 bhW = *(const short8*)(wh  + (size_t)c*8);
    short8 blW = *(const short8*)(wlo + (size_t)c*8);
    acc0 = __builtin_amdgcn_mfma_f32_16x16x32_bf16(a0h, bhW, acc0, 0,0,0);
    acc0 = __builtin_amdgcn_mfma_f32_16x16x32_bf16(a0l, bhW, acc0, 0,0,0);
    acc0 = __builtin_amdgcn_mfma_f32_16x16x32_bf16(a0h, blW, acc0, 0,0,0);
    acc1 = __builtin_amdgcn_mfma_f32_16x16x32_bf16(a1h, bhW, acc1, 0,0,0);
    acc1 = __builtin_amdgcn_mfma_f32_16x16x32_bf16(a1l, bhW, acc1, 0,0,0);
    acc1 = __builtin_amdgcn_mfma_f32_16x16x32_bf16(a1h, blW, acc1, 0,0,0);
  }
}

__global__ __launch_bounds__(512, 1) void lstm_pers(
    const float* __restrict__ x,    const float* __restrict__ h0in, const float* __restrict__ c0in,
    const float* __restrict__ wih0, const float* __restrict__ whh0,
    const float* __restrict__ bih0, const float* __restrict__ bhh0,
    const float* __restrict__ wih1, const float* __restrict__ whh1,
    const float* __restrict__ bih1, const float* __restrict__ bhh1,
    const float* __restrict__ wlin, const float* __restrict__ blin,
    float* __restrict__ out, float* ws)
{
  __shared__ __align__(16) unsigned short wlds_hi[32768];   // 65,536 B
  __shared__ __align__(16) unsigned short wlds_lo[32768];   // 65,536 B
  __shared__ __align__(16) float red[RED_TOT];              //  8,960 B
  __shared__ unsigned ctrl[16];                             // [0]=bar, [8]=done
  const int tid = threadIdx.x, wg = blockIdx.x;
  const int lane = tid & 63;
  const int wid  = tid >> 6;
  const int bgrp = wg & 1;
  const int half = (wg >> 1) & 1;      // 0: layer0, 1: layer1
  const int cg   = wg >> 2;            // 0..63
  const int colbase = cg*8;
  const int khalf = wid & 1;
  const int ntile = wid >> 1;

  unsigned* flags = (unsigned*)ws;                  // 4 domains x 64 lines
  unsigned* F0 = flags + (bgrp*2 + 0)*1024;
  unsigned* F1 = flags + (bgrp*2 + 1)*1024;
  unsigned* myF = half ? F1 : F0;
  unsigned* r0h = ((unsigned*)ws) + 5120;           // planes: [4 slot][2 bgrp][8192]
  unsigned* r0l = r0h + 65536;
  unsigned* r1h = r0h + 131072;
  unsigned* r1l = r0h + 196608;

  unsigned* xsh_s = (unsigned*)(wlds_hi + 20480);   // L0 WGs only (overlay)
  unsigned* xsl_s = (unsigned*)(wlds_lo + 20480);

  if (tid == 0){ ctrl[0] = 0; ctrl[8] = 0; }

  // ---- init (compute threads only) ----
  if (tid < 256){
    if (half == 0){
      for (int c = tid; c < 2560; c += 256){
        int kh = c / 1280; int rem = c - kh*1280;
        int kf = rem >> 7; int rem2 = rem & 127;
        int ks = rem2 >> 5; int n = rem2 & 31;
        int kk = kh*320 + kf*32 + ks*8;
        int wrow = (n>>3)*512 + colbase + (n&7);
        const float* src; long off;
        if (kk < 512){ src = whh0; off = (long)wrow*512 + kk; }
        else         { src = wih0; off = (long)wrow*128 + (kk-512); }
        float4 a = *(const float4*)(src + off);
        float4 b = *(const float4*)(src + off + 4);
        short8 hi, lo; cvt8(a, b, hi, lo);
        *(short8*)(wlds_hi + (size_t)c*8) = hi;
        *(short8*)(wlds_lo + (size_t)c*8) = lo;
      }
    } else {
      for (int c = tid; c < 4096; c += 256){
        int kh = c >> 11; int rem = c & 2047;
        int kf = rem >> 7; int rem2 = rem & 127;
        int ks = rem2 >> 5; int n = rem2 & 31;
        int kk = kh*512 + kf*32 + ks*8;
        int wrow = (n>>3)*512 + colbase + (n&7);
        const float* src; long off;
        if (kk < 512){ src = whh1; off = (long)wrow*512 + kk; }
        else         { src = wih1; off = (long)wrow*512 + (kk-512); }
        float4 a = *(const float4*)(src + off);
        float4 b = *(const float4*)(src + off + 4);
        short8 hi, lo; cvt8(a, b, hi, lo);
        *(short8*)(wlds_hi + (size_t)c*8) = hi;
        *(short8*)(wlds_lo + (size_t)c*8) = lo;
      }
    }
    {
      int e = cg*256 + tid;                  // [0, 16384) in (half,bgrp) slab
      if (!(e & 1)){
        int m = e >> 9;
        int col = e & 511;
        const float* src = h0in + half*32768 + (size_t)(bgrp*32+m)*512 + col;
        float v0 = src[0], v1 = src[1];
        unsigned short hA = f2bf(v0), lA = f2bf(v0 - bf2f(hA));
        unsigned short hB = f2bf(v1), lB = f2bf(v1 - bf2f(hB));
        unsigned uh = (unsigned)hA | ((unsigned)hB<<16);
        unsigned ul = (unsigned)lA | ((unsigned)lB<<16);
        int off = (col>>5)*512 + (m>>4)*256
                + (((m&15) | (((col>>3)&3)<<4))<<2) + ((col&7)>>1);
        unsigned* ph = (half ? r1h : r0h) + (0*2 + bgrp)*8192;
        unsigned* pl = (half ? r1l : r0l) + (0*2 + bgrp)*8192;
        st_agent_u32(ph + off, uh);
        st_agent_u32(pl + off, ul);
      }
    }
    if (half == 0){
      int m = tid>>3, dd = (tid&7)*16;
      const float* xp = x + ((size_t)(bgrp*32+m))*65536 + 0*128 + dd;
      float4 v0 = *(const float4*)xp,      v1 = *(const float4*)(xp+4),
             v2 = *(const float4*)(xp+8),  v3 = *(const float4*)(xp+12);
      float vv[16] = {v0.x,v0.y,v0.z,v0.w, v1.x,v1.y,v1.z,v1.w,
                      v2.x,v2.y,v2.z,v2.w, v3.x,v3.y,v3.z,v3.w};
      unsigned uh[8], ul[8];
      #pragma unroll
      for (int j=0;j<8;j++){
        unsigned short hA = f2bf(vv[2*j]),   hB = f2bf(vv[2*j+1]);
        unsigned short lA = f2bf(vv[2*j]-bf2f(hA)), lB = f2bf(vv[2*j+1]-bf2f(hB));
        uh[j] = (unsigned)hA | ((unsigned)hB<<16);
        ul[j] = (unsigned)lA | ((unsigned)lB<<16);
      }
      unsigned* dh = xsh_s + m*68 + (dd>>1);
      unsigned* dl = xsl_s + m*68 + (dd>>1);
      *(uint4*)dh     = make_uint4(uh[0],uh[1],uh[2],uh[3]);
      *(uint4*)(dh+4) = make_uint4(uh[4],uh[5],uh[6],uh[7]);
      *(uint4*)dl     = make_uint4(ul[0],ul[1],ul[2],ul[3]);
      *(uint4*)(dl+4) = make_uint4(ul[4],ul[5],ul[6],ul[7]);
    }
  }

  // ---- per-thread state ----
  const int m_l = (tid & 255) >> 3;
  const int cl  = tid & 7;
  const int col_own = colbase + cl;
  float biasr[4], cst;
  #pragma unroll
  for (int g=0; g<4; ++g){
    biasr[g] = half ? (bih1[g*512+col_own] + bhh1[g*512+col_own])
                    : (bih0[g*512+col_own] + bhh0[g*512+col_own]);
  }
  cst = c0in[half*32768 + (size_t)(bgrp*32+m_l)*512 + col_own];
  float blin_r = blin[0];
  const int c0p   = col_own & ~1;
  const int prodoff = (c0p>>5)*512 + (m_l>>4)*256
                    + (((m_l&15) | (((c0p>>3)&3)<<4))<<2) + ((c0p&7)>>1);

  float wl[8];
  {
    const float4* wp = (const float4*)wlin + (lane*2);
    float4 w0 = wp[0], w1 = wp[1];
    wl[0]=w0.x; wl[1]=w0.y; wl[2]=w0.z; wl[3]=w0.w;
    wl[4]=w1.x; wl[5]=w1.y; wl[6]=w1.z; wl[7]=w1.w;
  }
  const int yoff = (lane>>2)*512 + ((cg>>4)&1)*256
                 + ((((cg&15) | ((lane&3)<<4)))<<2);

  asm volatile("s_waitcnt vmcnt(0)" ::: "memory");
  __syncthreads();                       // all 512 threads, once
  if (tid == 0) st_agent_u32(&myF[cg*16], 1u);

  // ================== BURNER WAVES ==================
  if (tid >= 256){
    float a0=1e-30f, a1=1.00001e-30f, a2=1.00002e-30f, a3=1.00003e-30f;
    for(;;){
      if (__hip_atomic_load(&ctrl[8], __ATOMIC_RELAXED, __HIP_MEMORY_SCOPE_WORKGROUP)) break;
      #pragma unroll
      for (int i=0;i<16;i++){
        asm volatile("v_fmac_f32 %0,%1,%2":"+v"(a0):"v"(a1),"v"(a2));
        asm volatile("v_fmac_f32 %0,%1,%2":"+v"(a1):"v"(a2),"v"(a3));
        asm volatile("v_fmac_f32 %0,%1,%2":"+v"(a2):"v"(a3),"v"(a0));
        asm volatile("v_fmac_f32 %0,%1,%2":"+v"(a3):"v"(a0),"v"(a1));
      }
    }
    asm volatile("" :: "v"(a0),"v"(a1),"v"(a2),"v"(a3));
    return;
  }

  // ================== COMPUTE WAVES ==================
  const int m0loc = lane & 15;
  const int kslot = lane >> 4;
  const int nidx  = ntile*16 + (lane & 15);
  unsigned barph = 0;

  if (half == 0){
    // ---------- LAYER-0 GROUP ----------
    for (int t = 0; t < TT; ++t){
      pollwave2(F0, (unsigned)(t+1), F1, (unsigned)(t-2), t>=4, lane);
      barph += 4; cbar(&ctrl[0], barph, tid);   // orders prev-iter x-stage

      const unsigned* rAh = r0h + ((t&3)*2 + bgrp)*8192;  // h0(t-1)
      const unsigned* rAl = r0l + ((t&3)*2 + bgrp)*8192;
      const unsigned* xsh_t = xsh_s + (t&1)*2176;
      const unsigned* xsl_t = xsl_s + (t&1)*2176;
      f32x4 acc0 = {0.f,0.f,0.f,0.f}, acc1 = {0.f,0.f,0.f,0.f};
      if (khalf == 0) gates_mfma<10,0,0>(rAh,rAl,0,0,xsh_t,xsl_t,wlds_hi,wlds_lo,lane,m0loc,kslot,nidx,acc0,acc1);
      else            gates_mfma<10,0,1>(rAh,rAl,0,0,xsh_t,xsl_t,wlds_hi,wlds_lo,lane,m0loc,kslot,nidx,acc0,acc1);
      #pragma unroll
      for (int r=0; r<4; ++r){
        int mm = kslot*4 + r;
        red[RED(khalf, mm,    nidx)] = acc0[r];
        red[RED(khalf, 16+mm, nidx)] = acc1[r];
      }
      barph += 4; cbar(&ctrl[0], barph, tid);

      {
        float g4[4];
        #pragma unroll
        for (int g=0; g<4; ++g){
          int n = g*8 + cl;
          g4[g] = red[RED(0,m_l,n)] + red[RED(1,m_l,n)] + biasr[g];
        }
        float gi = fsigmoid(g4[0]);
        float gf = fsigmoid(g4[1]);
        float gg = ftanh   (g4[2]);
        float go = fsigmoid(g4[3]);
        float c = gf*cst + gi*gg;
        cst = c;
        float h = go * ftanh(c);
        float h_oth = __shfl_xor(h, 1, 64);
        if (!(tid & 1)){
          unsigned short hA = f2bf(h),     lA = f2bf(h - bf2f(hA));
          unsigned short hB = f2bf(h_oth), lB = f2bf(h_oth - bf2f(hB));
          unsigned uh = (unsigned)hA | ((unsigned)hB<<16);
          unsigned ul = (unsigned)lA | ((unsigned)lB<<16);
          int sbase = (((t+1)&3)*2 + bgrp)*8192;
          st_agent_u32(r0h + sbase + prodoff, uh);
          st_agent_u32(r0l + sbase + prodoff, ul);
        }
      }

      // y(t-4) BEFORE flag store (race-free per R14 proof); atomic reads
      if (t >= 4 && cg < 32 && wid == 0){
        int j = t - 4;
        int sbase = (((j+1)&3)*2 + bgrp)*8192;
        unsigned a4[4], b4[4];
        ld_ring16_u(r1h + sbase + yoff, a4);
        ld_ring16_u(r1l + sbase + yoff, b4);
        float p = 0.f;
        #pragma unroll
        for (int q=0;q<4;q++){
          unsigned qa=a4[q], qb=b4[q];
          float e0 = __uint_as_float(qa<<16) + __uint_as_float(qb<<16);
          float e1 = __uint_as_float(qa & 0xFFFF0000u) + __uint_as_float(qb & 0xFFFF0000u);
          p += e0*wl[2*q] + e1*wl[2*q+1];
        }
        #pragma unroll
        for (int m=1; m<64; m<<=1) p += __shfl_xor(p, m, 64);
        if (lane == 0) st_agent_f(&out[(bgrp*32+cg)*512 + j], p + blin_r);
      }

      asm volatile("s_waitcnt vmcnt(0)" ::: "memory");
      barph += 4; cbar(&ctrl[0], barph, tid);
      if (tid == 0) st_agent_u32(&F0[cg*16], (unsigned)(t+2));

      if (t+1 < TT){
        int m = tid>>3, dd = (tid&7)*16;
        const float* xp = x + ((size_t)(bgrp*32+m))*65536 + (size_t)(t+1)*128 + dd;
        float4 v0 = *(const float4*)xp,      v1 = *(const float4*)(xp+4),
               v2 = *(const float4*)(xp+8),  v3 = *(const float4*)(xp+12);
        float vv[16] = {v0.x,v0.y,v0.z,v0.w, v1.x,v1.y,v1.z,v1.w,
                        v2.x,v2.y,v2.z,v2.w, v3.x,v3.y,v3.z,v3.w};
        unsigned uh[8], ul[8];
        #pragma unroll
        for (int j=0;j<8;j++){
          unsigned short hA = f2bf(vv[2*j]),   hB = f2bf(vv[2*j+1]);
          unsigned short lA = f2bf(vv[2*j]-bf2f(hA)), lB = f2bf(vv[2*j+1]-bf2f(hB));
          uh[j] = (unsigned)hA | ((unsigned)hB<<16);
          ul[j] = (unsigned)lA | ((unsigned)lB<<16);
        }
        unsigned* dh = xsh_s + ((t+1)&1)*2176 + m*68 + (dd>>1);
        unsigned* dl = xsl_s + ((t+1)&1)*2176 + m*68 + (dd>>1);
        *(uint4*)dh     = make_uint4(uh[0],uh[1],uh[2],uh[3]);
        *(uint4*)(dh+4) = make_uint4(uh[4],uh[5],uh[6],uh[7]);
        *(uint4*)dl     = make_uint4(ul[0],ul[1],ul[2],ul[3]);
        *(uint4*)(dl+4) = make_uint4(ul[4],ul[5],ul[6],ul[7]);
      }
    }

    // epilogue: y(508..511)
    if (cg < 32 && wid == 0){
      pollwave(F1, (unsigned)(TT+1), lane);
      #pragma unroll
      for (int e=0; e<4; ++e){
        int j = TT-4+e;
        int sbase = (((j+1)&3)*2 + bgrp)*8192;
        unsigned a4[4], b4[4];
        ld_ring16_u(r1h + sbase + yoff, a4);
        ld_ring16_u(r1l + sbase + yoff, b4);
        float p = 0.f;
        #pragma unroll
        for (int q=0;q<4;q++){
          unsigned qa=a4[q], qb=b4[q];
          float e0 = __uint_as_float(qa<<16) + __uint_as_float(qb<<16);
          float e1 = __uint_as_float(qa & 0xFFFF0000u) + __uint_as_float(qb & 0xFFFF0000u);
          p += e0*wl[2*q] + e1*wl[2*q+1];
        }
        #pragma unroll
        for (int m=1; m<64; m<<=1) p += __shfl_xor(p, m, 64);
        if (lane == 0) st_agent_f(&out[(bgrp*32+cg)*512 + j], p + blin_r);
      }
    }
  } else {
    // ---------- LAYER-1 GROUP: pure recurrence ----------
    for (int s = 0; s < TT; ++s){
      if (khalf == 1) pollwave(F0, (unsigned)(s+2), lane);
      else            pollwave(F1, (unsigned)(s+1), lane);

      const unsigned* rAh = r1h + ((s&3)*2 + bgrp)*8192;      // h1(s-1)
      const unsigned* rAl = r1l + ((s&3)*2 + bgrp)*8192;
      const unsigned* rBh = r0h + (((s+1)&3)*2 + bgrp)*8192;  // h0(s)
      const unsigned* rBl = r0l + (((s+1)&3)*2 + bgrp)*8192;
      f32x4 acc0 = {0.f,0.f,0.f,0.f}, acc1 = {0.f,0.f,0.f,0.f};
      if (khalf == 0) gates_mfma<16,1,0>(rAh,rAl,rBh,rBl,0,0,wlds_hi,wlds_lo,lane,m0loc,kslot,nidx,acc0,acc1);
      else            gates_mfma<16,1,1>(rAh,rAl,rBh,rBl,0,0,wlds_hi,wlds_lo,lane,m0loc,kslot,nidx,acc0,acc1);
      #pragma unroll
      for (int r=0; r<4; ++r){
        int mm = kslot*4 + r;
        red[RED(khalf, mm,    nidx)] = acc0[r];
        red[RED(khalf, 16+mm, nidx)] = acc1[r];
      }
      barph += 4; cbar(&ctrl[0], barph, tid);   // sync1: joins split waves

      {
        float g4[4];
        #pragma unroll
        for (int g=0; g<4; ++g){
          int n = g*8 + cl;
          g4[g] = red[RED(0,m_l,n)] + red[RED(1,m_l,n)] + biasr[g];
        }
        float gi = fsigmoid(g4[0]);
        float gf = fsigmoid(g4[1]);
        float gg = ftanh   (g4[2]);
        float go = fsigmoid(g4[3]);
        float c = gf*cst + gi*gg;
        cst = c;
        float h = go * ftanh(c);
        float h_oth = __shfl_xor(h, 1, 64);
        if (!(tid & 1)){
          unsigned short hA = f2bf(h),     lA = f2bf(h - bf2f(hA));
          unsigned short hB = f2bf(h_oth), lB = f2bf(h_oth - bf2f(hB));
          unsigned uh = (unsigned)hA | ((unsigned)hB<<16);
          unsigned ul = (unsigned)lA | ((unsigned)lB<<16);
          int sbase = (((s+1)&3)*2 + bgrp)*8192;
          st_agent_u32(r1h + sbase + prodoff, uh);
          st_agent_u32(r1l + sbase + prodoff, ul);
        }
      }
      asm volatile("s_waitcnt vmcnt(0)" ::: "memory");
      barph += 4; cbar(&ctrl[0], barph, tid);   // sync2
      if (tid == 0) st_agent_u32(&F1[cg*16], (unsigned)(s+2));
    }
  }

  // stop burners
  if (tid == 0)
    __hip_atomic_store(&ctrl[8], 1u, __ATOMIC_RELEASE, __HIP_MEMORY_SCOPE_WORKGROUP);
}

extern "C" void kernel_launch(void* const* d_in, const int* in_sizes, int n_in,
                              void* d_out, int out_size, void* d_ws, size_t ws_size,
                              hipStream_t stream)
{
  (void)in_sizes; (void)n_in; (void)out_size; (void)ws_size;
  const float* x    = (const float*)d_in[0];
  const float* h0   = (const float*)d_in[1];
  const float* c0   = (const float*)d_in[2];
  const float* wih0 = (const float*)d_in[3];
  const float* whh0 = (const float*)d_in[4];
  const float* bih0 = (const float*)d_in[5];
  const float* bhh0 = (const float*)d_in[6];
  const float* wih1 = (const float*)d_in[7];
  const float* whh1 = (const float*)d_in[8];
  const float* bih1 = (const float*)d_in[9];
  const float* bhh1 = (const float*)d_in[10];
  const float* wlin = (const float*)d_in[11];
  const float* blin = (const float*)d_in[12];
  float* outp = (float*)d_out;
  float* wsp  = (float*)d_ws;

  hipMemsetAsync(d_ws, 0, 18432, stream);

  void* args[] = { &x, &h0, &c0, &wih0, &whh0, &bih0, &bhh0,
                   &wih1, &whh1, &bih1, &bhh1, &wlin, &blin, &outp, &wsp };
  hipError_t err = hipLaunchCooperativeKernel((const void*)lstm_pers,
                                              dim3(NWG), dim3(512), args, 0, stream);
  if (err != hipSuccess){
    // Fallback: 1 block/CU (140KB LDS), 256 blocks on 256 CUs -> co-resident.
    hipLaunchKernelGGL(lstm_pers, dim3(NWG), dim3(512), 0, stream,
                       x, h0, c0, wih0, whh0, bih0, bhh0,
                       wih1, whh1, bih1, bhh1, wlin, blin, outp, wsp);
  }
}

// Round 18
// 3490.818 us; speedup vs baseline: 2.2506x; 1.0813x over previous
//
#include <hip/hip_runtime.h>
#include <math.h>

// Persistent cooperative 2-layer LSTM. Round 18: FENCE-FREE WAVE-AUTONOMY.
// = R15's wave-autonomous engines (full-K per wave, 16 batches x 4 cols x
// 4 gates, in-wave 4x4 shuffle transpose -> 1 cell/lane, per-wave flags)
// + R17's coherence protocol (NO agent-acquire fences anywhere in the loops;
// ring reads are 64-bit relaxed agent atomic loads served at L3; producer:
// agent write-through stores + vmcnt(0) drain BEFORE flag)
// + R16's burner waves (tid>=256 spin FMAs -> SCLK stays up).
// No __syncthreads / no LDS exchange / no cbar in the main loops.
// Load overlap: L1 waves load h0(s) chunks after the early-satisfied F0 poll
// BEFORE polling F1; L0 waves load x chunks before any poll.
// Split precision MFMA: gates = Whi*hhi + Whi*hlo + Wlo*hhi (fp32 acc).
//
// ws layout (bytes): flags 4 domains x 256 lines x 64B @0 (64KB);
// uints @16384: r0h[4 slot][2 bgrp][8192], r0l, r1h, r1l (256KB/plane, 1MB).

#define TT 512
#define NWG 256

typedef __attribute__((ext_vector_type(8))) short short8;
typedef __attribute__((ext_vector_type(4))) float f32x4;

__device__ __forceinline__ float fsigmoid(float v){ return 1.f/(1.f+__expf(-v)); }
__device__ __forceinline__ float ftanh(float v){ return 2.f/(1.f+__expf(-2.f*v)) - 1.f; }

__device__ __forceinline__ unsigned short f2bf(float f){
  unsigned u = __float_as_uint(f);
  unsigned r = ((u>>16)&1u) + 0x7FFFu;
  return (unsigned short)((u + r)>>16);
}
__device__ __forceinline__ float bf2f(unsigned short s){
  return __uint_as_float(((unsigned)s)<<16);
}
__device__ __forceinline__ void cvt8(const float4& a, const float4& b,
                                     short8& hi, short8& lo){
  float v[8] = {a.x,a.y,a.z,a.w,b.x,b.y,b.z,b.w};
  #pragma unroll
  for (int i=0;i<8;i++){
    unsigned short h = f2bf(v[i]);
    unsigned short l = f2bf(v[i] - bf2f(h));
    ((unsigned short*)&hi)[i] = h;
    ((unsigned short*)&lo)[i] = l;
  }
}

__device__ __forceinline__ void st_agent_f(float* p, float v){
  __hip_atomic_store(p, v, __ATOMIC_RELAXED, __HIP_MEMORY_SCOPE_AGENT);
}
__device__ __forceinline__ void st_agent_u32(unsigned* p, unsigned v){
  __hip_atomic_store(p, v, __ATOMIC_RELAXED, __HIP_MEMORY_SCOPE_AGENT);
}
__device__ __forceinline__ unsigned ldflag(const unsigned* p){
  return __hip_atomic_load(p, __ATOMIC_RELAXED, __HIP_MEMORY_SCOPE_AGENT);
}

// Coherent 16B ring read: two 64-bit relaxed agent atomic loads (L3-served,
// bypass stale L1/L2) - proven R10-R17.
__device__ __forceinline__ short8 ld_ring16(const unsigned* p){
  const unsigned long long* q = (const unsigned long long*)p;
  union { unsigned long long u[2]; short8 s; } v;
  v.u[0] = __hip_atomic_load(&q[0], __ATOMIC_RELAXED, __HIP_MEMORY_SCOPE_AGENT);
  v.u[1] = __hip_atomic_load(&q[1], __ATOMIC_RELAXED, __HIP_MEMORY_SCOPE_AGENT);
  return v.s;
}
__device__ __forceinline__ void ld_ring16_u(const unsigned* p, unsigned o[4]){
  const unsigned long long* q = (const unsigned long long*)p;
  unsigned long long a = __hip_atomic_load(&q[0], __ATOMIC_RELAXED, __HIP_MEMORY_SCOPE_AGENT);
  unsigned long long b = __hip_atomic_load(&q[1], __ATOMIC_RELAXED, __HIP_MEMORY_SCOPE_AGENT);
  o[0] = (unsigned)a; o[1] = (unsigned)(a>>32);
  o[2] = (unsigned)b; o[3] = (unsigned)(b>>32);
}

// Poll two specific flag lines (wave-uniform progress via __all).
__device__ __forceinline__ void poll2(const unsigned* a, const unsigned* b, unsigned need){
  int it = 0;
  for(;;){
    bool ok = (ldflag(a) >= need) & (ldflag(b) >= need);
    if (__all(ok)) break;
    if (++it > 8) __builtin_amdgcn_s_sleep(1);
  }
}
__device__ __forceinline__ void poll4(const unsigned* a, const unsigned* b,
                                      const unsigned* c, const unsigned* d, unsigned need){
  int it = 0;
  for(;;){
    bool ok = (ldflag(a) >= need) & (ldflag(b) >= need)
            & (ldflag(c) >= need) & (ldflag(d) >= need);
    if (__all(ok)) break;
    if (++it > 8) __builtin_amdgcn_s_sleep(1);
  }
}

__global__ __launch_bounds__(512, 1) void lstm_pers(
    const float* __restrict__ x,    const float* __restrict__ h0in, const float* __restrict__ c0in,
    const float* __restrict__ wih0, const float* __restrict__ whh0,
    const float* __restrict__ bih0, const float* __restrict__ bhh0,
    const float* __restrict__ wih1, const float* __restrict__ whh1,
    const float* __restrict__ bih1, const float* __restrict__ bhh1,
    const float* __restrict__ wlin, const float* __restrict__ blin,
    float* __restrict__ out, float* ws)
{
  __shared__ __align__(16) unsigned short wlds_hi[32768];   // 64 KB
  __shared__ __align__(16) unsigned short wlds_lo[32768];   // 64 KB
  __shared__ unsigned ctrl[16];                             // [8]=done
  const int tid = threadIdx.x, wg = blockIdx.x;
  const int lane = tid & 63;
  const int wid  = tid >> 6;           // compute waves: 0..3
  const int mtile = wid >> 1;
  const int ntile = wid & 1;
  const int bgrp = wg & 1;
  const int half = (wg >> 1) & 1;      // 0: layer0, 1: layer1
  const int cg   = wg >> 2;            // 0..63
  const int colbase = cg*8;

  unsigned* flags = (unsigned*)ws;                  // 4 domains x 256 lines
  unsigned* F0 = flags + (bgrp*2 + 0)*4096;
  unsigned* F1 = flags + (bgrp*2 + 1)*4096;
  unsigned* myF = half ? F1 : F0;
  unsigned* rbase = ((unsigned*)ws) + 16384;        // byte 65536
  unsigned* r0h = rbase;                            // [4 slot][2 bgrp][8192]
  unsigned* r0l = rbase + 65536;
  unsigned* r1h = rbase + 131072;
  unsigned* r1l = rbase + 196608;

  if (tid == 0) ctrl[8] = 0;

  // ---- init (compute threads only): W into LDS (ntile-major), h(-1) ----
  if (tid < 256){
    if (half == 0){
      for (int c = tid; c < 2560; c += 256){          // NC=20
        int nt = c / 1280; int rem = c - nt*1280;
        int ch = rem >> 6; int ks = (rem>>4)&3; int n = rem & 15;
        int kk = ch*32 + ks*8;
        int wrow = (n>>2)*512 + colbase + nt*4 + (n&3);
        const float* src; long off;
        if (kk < 512){ src = whh0; off = (long)wrow*512 + kk; }
        else         { src = wih0; off = (long)wrow*128 + (kk-512); }
        float4 a = *(const float4*)(src + off);
        float4 b = *(const float4*)(src + off + 4);
        short8 hi, lo; cvt8(a, b, hi, lo);
        *(short8*)(wlds_hi + (size_t)c*8) = hi;
        *(short8*)(wlds_lo + (size_t)c*8) = lo;
      }
    } else {
      for (int c = tid; c < 4096; c += 256){          // NC=32
        int nt = c >> 11; int rem = c & 2047;
        int ch = rem >> 6; int ks = (rem>>4)&3; int n = rem & 15;
        int kk = ch*32 + ks*8;
        int wrow = (n>>2)*512 + colbase + nt*4 + (n&3);
        const float* src; long off;
        if (kk < 512){ src = whh1; off = (long)wrow*512 + kk; }
        else         { src = wih1; off = (long)wrow*512 + (kk-512); }
        float4 a = *(const float4*)(src + off);
        float4 b = *(const float4*)(src + off + 4);
        short8 hi, lo; cvt8(a, b, hi, lo);
        *(short8*)(wlds_hi + (size_t)c*8) = hi;
        *(short8*)(wlds_lo + (size_t)c*8) = lo;
      }
    }
    {
      int e = cg*256 + tid;                  // [0, 16384) in (half,bgrp) slab
      if (!(e & 1)){
        int m = e >> 9;
        int col = e & 511;
        const float* src = h0in + half*32768 + (size_t)(bgrp*32+m)*512 + col;
        float v0 = src[0], v1 = src[1];
        unsigned short hA = f2bf(v0), lA = f2bf(v0 - bf2f(hA));
        unsigned short hB = f2bf(v1), lB = f2bf(v1 - bf2f(hB));
        unsigned uh = (unsigned)hA | ((unsigned)hB<<16);
        unsigned ul = (unsigned)lA | ((unsigned)lB<<16);
        int off = (col>>5)*512 + (m>>4)*256
                + (((m&15) | (((col>>3)&3)<<4))<<2) + ((col&7)>>1);
        unsigned* ph = (half ? r1h : r0h) + (0*2 + bgrp)*8192;
        unsigned* pl = (half ? r1l : r0l) + (0*2 + bgrp)*8192;
        st_agent_u32(ph + off, uh);
        st_agent_u32(pl + off, ul);
      }
    }
  }

  // ---- per-lane cell state (1 cell/lane after transpose) ----
  const int jpos = (lane>>2)&3;
  const int cc   = lane&3;
  const int col_own = colbase + ntile*4 + cc;
  const int bl_own  = mtile*16 + (lane>>4)*4 + jpos;   // local batch 0..31
  float biasr[4], cst;
  #pragma unroll
  for (int g=0; g<4; ++g){
    biasr[g] = half ? (bih1[g*512+col_own] + bhh1[g*512+col_own])
                    : (bih0[g*512+col_own] + bhh0[g*512+col_own]);
  }
  cst = c0in[half*32768 + (size_t)(bgrp*32+bl_own)*512 + col_own];
  float blin_r = blin[0];
  const int c0p = col_own & ~1;
  const int prodoff = (c0p>>5)*512 + (bl_own>>4)*256
                    + (((bl_own&15) | (((c0p>>3)&3)<<4))<<2) + ((c0p&7)>>1);

  // ---- y-role state ----
  float wl[8];
  {
    const float4* wp = (const float4*)wlin + (lane*2);
    float4 w0 = wp[0], w1 = wp[1];
    wl[0]=w0.x; wl[1]=w0.y; wl[2]=w0.z; wl[3]=w0.w;
    wl[4]=w1.x; wl[5]=w1.y; wl[6]=w1.z; wl[7]=w1.w;
  }
  const int yoff = (lane>>2)*512 + ((cg>>4)&1)*256
                 + ((((cg&15) | ((lane&3)<<4)))<<2);

  asm volatile("s_waitcnt vmcnt(0)" ::: "memory");
  __syncthreads();                       // once, all 512 threads
  if (tid < 256 && lane == 0) st_agent_u32(&myF[(cg*4 + wid)*16], 1u);

  // ================== BURNER WAVES ==================
  if (tid >= 256){
    float a0=1e-30f, a1=1.00001e-30f, a2=1.00002e-30f, a3=1.00003e-30f;
    for(;;){
      if (__hip_atomic_load(&ctrl[8], __ATOMIC_RELAXED, __HIP_MEMORY_SCOPE_WORKGROUP)) break;
      #pragma unroll
      for (int i=0;i<16;i++){
        asm volatile("v_fmac_f32 %0,%1,%2":"+v"(a0):"v"(a1),"v"(a2));
        asm volatile("v_fmac_f32 %0,%1,%2":"+v"(a1):"v"(a2),"v"(a3));
        asm volatile("v_fmac_f32 %0,%1,%2":"+v"(a2):"v"(a3),"v"(a0));
        asm volatile("v_fmac_f32 %0,%1,%2":"+v"(a3):"v"(a0),"v"(a1));
      }
    }
    asm volatile("" :: "v"(a0),"v"(a1),"v"(a2),"v"(a3));
    return;
  }

  // ================== COMPUTE WAVES (autonomous) ==================
  const int kslot = lane >> 4;
  const int nlane = lane & 15;
  const int aoff  = mtile*256 + lane*4;       // + chunk*512, uints
  const size_t xrow = (size_t)(bgrp*32 + mtile*16 + nlane)*65536;

  // mtile-matched flag lines (lane -> producer WG cg'=lane, waves 2m,2m+1)
  const unsigned* pF0a = F0 + (lane*4 + mtile*2)*16;
  const unsigned* pF0b = pF0a + 16;
  const unsigned* pF1a = F1 + (lane*4 + mtile*2)*16;
  const unsigned* pF1b = pF1a + 16;

  if (half == 0){
    // ================= LAYER-0 WAVES =================
    const bool isy = (cg < 32) && (wid == ((cg>>4)<<1));
    for (int t = 0; t < TT; ++t){
      f32x4 acc = {0.f,0.f,0.f,0.f};
      // x chunks 16..19 FIRST (pure input; overlaps the poll below)
      #pragma unroll
      for (int ch=16; ch<20; ++ch){
        int d = ch*32 + kslot*8 - 512;
        const float* xp = x + xrow + (size_t)t*128 + d;
        float4 u0 = *(const float4*)xp, u1 = *(const float4*)(xp+4);
        short8 ah, al; cvt8(u0,u1,ah,al);
        int c = ((ntile*20 + ch)*4 + kslot)*16 + nlane;
        short8 wh8 = *(const short8*)(wlds_hi + (size_t)c*8);
        short8 wl8 = *(const short8*)(wlds_lo + (size_t)c*8);
        acc = __builtin_amdgcn_mfma_f32_16x16x32_bf16(ah, wh8, acc, 0,0,0);
        acc = __builtin_amdgcn_mfma_f32_16x16x32_bf16(al, wh8, acc, 0,0,0);
        acc = __builtin_amdgcn_mfma_f32_16x16x32_bf16(ah, wl8, acc, 0,0,0);
      }
      // poll: h0(t-1) rows (mtile) ready; backpressure (slot + y input) t>=4
      poll2(pF0a, pF0b, (unsigned)(t+1));
      if (t >= 4) poll2(pF1a, pF1b, (unsigned)(t-2));

      const unsigned* rAh = r0h + ((t&3)*2 + bgrp)*8192;   // h0(t-1)
      const unsigned* rAl = r0l + ((t&3)*2 + bgrp)*8192;
      #pragma unroll
      for (int ch=0; ch<16; ++ch){
        int o = ch*512 + aoff;
        short8 ah = ld_ring16(rAh + o);
        short8 al = ld_ring16(rAl + o);
        int c = ((ntile*20 + ch)*4 + kslot)*16 + nlane;
        short8 wh8 = *(const short8*)(wlds_hi + (size_t)c*8);
        short8 wl8 = *(const short8*)(wlds_lo + (size_t)c*8);
        acc = __builtin_amdgcn_mfma_f32_16x16x32_bf16(ah, wh8, acc, 0,0,0);
        acc = __builtin_amdgcn_mfma_f32_16x16x32_bf16(al, wh8, acc, 0,0,0);
        acc = __builtin_amdgcn_mfma_f32_16x16x32_bf16(ah, wl8, acc, 0,0,0);
      }
      // in-wave 4x4 transpose (lanes ^4, ^8): lane ends with all 4 gates
      float v0=acc[0], v1=acc[1], v2=acc[2], v3=acc[3];
      { bool b0 = (jpos & 1) != 0;
        float s0 = b0 ? v0 : v1, s1 = b0 ? v2 : v3;
        float r0 = __shfl_xor(s0, 4, 64), r1 = __shfl_xor(s1, 4, 64);
        if (b0){ v0=r0; v2=r1; } else { v1=r0; v3=r1; }
      }
      { bool b1 = ((jpos>>1) & 1) != 0;
        float s0 = b1 ? v0 : v2, s1 = b1 ? v1 : v3;
        float r0 = __shfl_xor(s0, 8, 64), r1 = __shfl_xor(s1, 8, 64);
        if (b1){ v0=r0; v1=r1; } else { v2=r0; v3=r1; }
      }
      float gi = fsigmoid(v0 + biasr[0]);
      float gf = fsigmoid(v1 + biasr[1]);
      float gg = ftanh   (v2 + biasr[2]);
      float go = fsigmoid(v3 + biasr[3]);
      float c_ = gf*cst + gi*gg; cst = c_;
      float h = go * ftanh(c_);
      float h_oth = __shfl_xor(h, 1, 64);
      if (!(lane & 1)){
        unsigned short hA = f2bf(h),     lA = f2bf(h - bf2f(hA));
        unsigned short hB = f2bf(h_oth), lB = f2bf(h_oth - bf2f(hB));
        unsigned uh = (unsigned)hA | ((unsigned)hB<<16);
        unsigned ul = (unsigned)lA | ((unsigned)lB<<16);
        int sbase = (((t+1)&3)*2 + bgrp)*8192;
        st_agent_u32(r0h + sbase + prodoff, uh);
        st_agent_u32(r0l + sbase + prodoff, ul);
      }
      // y(t-4) BEFORE flag: overwrite gated on F0>=t+2 (published below)
      if (isy && t >= 4){
        int j = t - 4;
        int sbase = (((t-3)&3)*2 + bgrp)*8192;
        unsigned a4[4], b4[4];
        ld_ring16_u(r1h + sbase + yoff, a4);
        ld_ring16_u(r1l + sbase + yoff, b4);
        float p = 0.f;
        #pragma unroll
        for (int q=0;q<4;q++){
          unsigned qa=a4[q], qb=b4[q];
          float e0 = __uint_as_float(qa<<16) + __uint_as_float(qb<<16);
          float e1 = __uint_as_float(qa & 0xFFFF0000u) + __uint_as_float(qb & 0xFFFF0000u);
          p += e0*wl[2*q] + e1*wl[2*q+1];
        }
        #pragma unroll
        for (int m=1; m<64; m<<=1) p += __shfl_xor(p, m, 64);
        if (lane == 0) st_agent_f(&out[(bgrp*32+cg)*512 + j], p + blin_r);
      }
      asm volatile("s_waitcnt vmcnt(0)" ::: "memory");
      if (lane == 0) st_agent_u32(&F0[(cg*4 + wid)*16], (unsigned)(t+2));
    }
    // epilogue: y(508..511)
    if (isy){
      poll2(pF1a, pF1b, (unsigned)(TT+1));
      #pragma unroll
      for (int e=0; e<4; ++e){
        int j = TT-4+e;
        int sbase = (((j+1)&3)*2 + bgrp)*8192;
        unsigned a4[4], b4[4];
        ld_ring16_u(r1h + sbase + yoff, a4);
        ld_ring16_u(r1l + sbase + yoff, b4);
        float p = 0.f;
        #pragma unroll
        for (int q=0;q<4;q++){
          unsigned qa=a4[q], qb=b4[q];
          float e0 = __uint_as_float(qa<<16) + __uint_as_float(qb<<16);
          float e1 = __uint_as_float(qa & 0xFFFF0000u) + __uint_as_float(qb & 0xFFFF0000u);
          p += e0*wl[2*q] + e1*wl[2*q+1];
        }
        #pragma unroll
        for (int m=1; m<64; m<<=1) p += __shfl_xor(p, m, 64);
        if (lane == 0) st_agent_f(&out[(bgrp*32+cg)*512 + j], p + blin_r);
      }
    }
  } else {
    // ================= LAYER-1 WAVES =================
    for (int s = 0; s < TT; ++s){
      // phase 1: h0(s) (early-satisfied poll; overlaps peers' F1 wait)
      poll2(pF0a, pF0b, (unsigned)(s+2));
      const unsigned* rBh = r0h + (((s+1)&3)*2 + bgrp)*8192;  // h0(s)
      const unsigned* rBl = r0l + (((s+1)&3)*2 + bgrp)*8192;
      f32x4 acc = {0.f,0.f,0.f,0.f};
      #pragma unroll
      for (int ch=16; ch<32; ++ch){
        int o = (ch-16)*512 + aoff;
        short8 ah = ld_ring16(rBh + o);
        short8 al = ld_ring16(rBl + o);
        int c = ((ntile*32 + ch)*4 + kslot)*16 + nlane;
        short8 wh8 = *(const short8*)(wlds_hi + (size_t)c*8);
        short8 wl8 = *(const short8*)(wlds_lo + (size_t)c*8);
        acc = __builtin_amdgcn_mfma_f32_16x16x32_bf16(ah, wh8, acc, 0,0,0);
        acc = __builtin_amdgcn_mfma_f32_16x16x32_bf16(al, wh8, acc, 0,0,0);
        acc = __builtin_amdgcn_mfma_f32_16x16x32_bf16(ah, wl8, acc, 0,0,0);
      }
      // phase 2: h1(s-1) (the critical chain)
      poll2(pF1a, pF1b, (unsigned)(s+1));
      const unsigned* rAh = r1h + ((s&3)*2 + bgrp)*8192;      // h1(s-1)
      const unsigned* rAl = r1l + ((s&3)*2 + bgrp)*8192;
      #pragma unroll
      for (int ch=0; ch<16; ++ch){
        int o = ch*512 + aoff;
        short8 ah = ld_ring16(rAh + o);
        short8 al = ld_ring16(rAl + o);
        int c = ((ntile*32 + ch)*4 + kslot)*16 + nlane;
        short8 wh8 = *(const short8*)(wlds_hi + (size_t)c*8);
        short8 wl8 = *(const short8*)(wlds_lo + (size_t)c*8);
        acc = __builtin_amdgcn_mfma_f32_16x16x32_bf16(ah, wh8, acc, 0,0,0);
        acc = __builtin_amdgcn_mfma_f32_16x16x32_bf16(al, wh8, acc, 0,0,0);
        acc = __builtin_amdgcn_mfma_f32_16x16x32_bf16(ah, wl8, acc, 0,0,0);
      }
      float v0=acc[0], v1=acc[1], v2=acc[2], v3=acc[3];
      { bool b0 = (jpos & 1) != 0;
        float s0 = b0 ? v0 : v1, s1 = b0 ? v2 : v3;
        float r0 = __shfl_xor(s0, 4, 64), r1 = __shfl_xor(s1, 4, 64);
        if (b0){ v0=r0; v2=r1; } else { v1=r0; v3=r1; }
      }
      { bool b1 = ((jpos>>1) & 1) != 0;
        float s0 = b1 ? v0 : v2, s1 = b1 ? v1 : v3;
        float r0 = __shfl_xor(s0, 8, 64), r1 = __shfl_xor(s1, 8, 64);
        if (b1){ v0=r0; v1=r1; } else { v2=r0; v3=r1; }
      }
      float gi = fsigmoid(v0 + biasr[0]);
      float gf = fsigmoid(v1 + biasr[1]);
      float gg = ftanh   (v2 + biasr[2]);
      float go = fsigmoid(v3 + biasr[3]);
      float c_ = gf*cst + gi*gg; cst = c_;
      float h = go * ftanh(c_);
      float h_oth = __shfl_xor(h, 1, 64);
      if (!(lane & 1)){
        unsigned short hA = f2bf(h),     lA = f2bf(h - bf2f(hA));
        unsigned short hB = f2bf(h_oth), lB = f2bf(h_oth - bf2f(hB));
        unsigned uh = (unsigned)hA | ((unsigned)hB<<16);
        unsigned ul = (unsigned)lA | ((unsigned)lB<<16);
        int sbase = (((s+1)&3)*2 + bgrp)*8192;
        st_agent_u32(r1h + sbase + prodoff, uh);
        st_agent_u32(r1l + sbase + prodoff, ul);
      }
      asm volatile("s_waitcnt vmcnt(0)" ::: "memory");
      if (lane == 0) st_agent_u32(&F1[(cg*4 + wid)*16], (unsigned)(s+2));
    }
  }

  // stop burners (first finishing wave; tail droop negligible)
  if (lane == 0)
    __hip_atomic_store(&ctrl[8], 1u, __ATOMIC_RELEASE, __HIP_MEMORY_SCOPE_WORKGROUP);
}

extern "C" void kernel_launch(void* const* d_in, const int* in_sizes, int n_in,
                              void* d_out, int out_size, void* d_ws, size_t ws_size,
                              hipStream_t stream)
{
  (void)in_sizes; (void)n_in; (void)out_size; (void)ws_size;
  const float* x    = (const float*)d_in[0];
  const float* h0   = (const float*)d_in[1];
  const float* c0   = (const float*)d_in[2];
  const float* wih0 = (const float*)d_in[3];
  const float* whh0 = (const float*)d_in[4];
  const float* bih0 = (const float*)d_in[5];
  const float* bhh0 = (const float*)d_in[6];
  const float* wih1 = (const float*)d_in[7];
  const float* whh1 = (const float*)d_in[8];
  const float* bih1 = (const float*)d_in[9];
  const float* bhh1 = (const float*)d_in[10];
  const float* wlin = (const float*)d_in[11];
  const float* blin = (const float*)d_in[12];
  float* outp = (float*)d_out;
  float* wsp  = (float*)d_ws;

  // zero per-wave flag lines (64KB); rings fully rewritten each launch
  hipMemsetAsync(d_ws, 0, 65536, stream);

  void* args[] = { &x, &h0, &c0, &wih0, &whh0, &bih0, &bhh0,
                   &wih1, &whh1, &bih1, &bhh1, &wlin, &blin, &outp, &wsp };
  hipError_t err = hipLaunchCooperativeKernel((const void*)lstm_pers,
                                              dim3(NWG), dim3(512), args, 0, stream);
  if (err != hipSuccess){
    // Fallback: 1 block/CU (128KB LDS), 256 blocks on 256 CUs -> co-resident.
    hipLaunchKernelGGL(lstm_pers, dim3(NWG), dim3(512), 0, stream,
                       x, h0, c0, wih0, whh0, bih0, bhh0,
                       wih1, whh1, bih1, bhh1, wlin, blin, outp, wsp);
  }
}